// Round 1
// baseline (496.493 us; speedup 1.0000x reference)
//
#include <hip/hip_runtime.h>
#include <hip/hip_bf16.h>
#include <math.h>

typedef __attribute__((ext_vector_type(8))) short bf16x8;
typedef __attribute__((ext_vector_type(4))) float f32x4;

#define MFMA16(a, b, c) __builtin_amdgcn_mfma_f32_16x16x32_bf16((a), (b), (c), 0, 0, 0)

// ---------------------------------------------------------------------------
// Transpose + fp32 -> bf16 convert:  in[K][N] f32  ->  out[N][K] bf16
// ---------------------------------------------------------------------------
__global__ __launch_bounds__(256)
void transpose_to_bf16(const float* __restrict__ in, __hip_bfloat16* __restrict__ out,
                       int K, int N)
{
    __shared__ float t[32][33];
    const int tx = threadIdx.x & 31, ty = threadIdx.x >> 5;  // ty: 0..7
    const int n0 = blockIdx.x * 32, k0 = blockIdx.y * 32;
    #pragma unroll
    for (int j = 0; j < 32; j += 8)
        t[ty + j][tx] = in[(size_t)(k0 + ty + j) * N + n0 + tx];
    __syncthreads();
    #pragma unroll
    for (int j = 0; j < 32; j += 8)
        out[(size_t)(n0 + ty + j) * K + k0 + tx] = __float2bfloat16(t[tx][ty + j]);
}

// ---------------------------------------------------------------------------
// LayerNorm over D=1024, one block per row, fp32 in -> bf16 out
// ---------------------------------------------------------------------------
__global__ __launch_bounds__(256)
void ln_kernel(const float* __restrict__ in, const float* __restrict__ w,
               const float* __restrict__ b, __hip_bfloat16* __restrict__ out)
{
    const int row = blockIdx.x;
    const int tid = threadIdx.x;
    const float4 v = reinterpret_cast<const float4*>(in + (size_t)row * 1024)[tid];
    float s  = v.x + v.y + v.z + v.w;
    float s2 = v.x * v.x + v.y * v.y + v.z * v.z + v.w * v.w;
    #pragma unroll
    for (int off = 32; off > 0; off >>= 1) {
        s  += __shfl_down(s,  off);
        s2 += __shfl_down(s2, off);
    }
    __shared__ float red[8];
    const int wv = tid >> 6, ln = tid & 63;
    if (ln == 0) { red[wv] = s; red[4 + wv] = s2; }
    __syncthreads();
    s  = red[0] + red[1] + red[2] + red[3];
    s2 = red[4] + red[5] + red[6] + red[7];
    const float mu   = s * (1.0f / 1024.0f);
    const float var  = s2 * (1.0f / 1024.0f) - mu * mu;
    const float rstd = rsqrtf(var + 1e-5f);
    const float4 wv4 = reinterpret_cast<const float4*>(w)[tid];
    const float4 bv4 = reinterpret_cast<const float4*>(b)[tid];
    const size_t o = (size_t)row * 1024 + tid * 4;
    out[o + 0] = __float2bfloat16((v.x - mu) * rstd * wv4.x + bv4.x);
    out[o + 1] = __float2bfloat16((v.y - mu) * rstd * wv4.y + bv4.y);
    out[o + 2] = __float2bfloat16((v.z - mu) * rstd * wv4.z + bv4.z);
    out[o + 3] = __float2bfloat16((v.w - mu) * rstd * wv4.w + bv4.w);
}

// ---------------------------------------------------------------------------
// GEMM: C[M][N] = A[M][K](bf16) * Bt[N][K](bf16)^T + bias (+gelu) (+resid f32)
// 128x128 tile, BK=32, 4 waves, 4x4 16x16 sub-tiles per wave.
// ---------------------------------------------------------------------------
template<bool OUT_BF16, bool GELU, bool RESID>
__global__ __launch_bounds__(256)
void gemm_kernel(const __hip_bfloat16* __restrict__ A,
                 const __hip_bfloat16* __restrict__ Bt,
                 const float* __restrict__ bias,
                 const float* __restrict__ resid,
                 void* __restrict__ Cout,
                 int M, int N, int K)
{
    constexpr int LDK = 40;  // 32 + 8 pad: row stride 80B -> 2-way bank alias (free)
    __shared__ __align__(16) __hip_bfloat16 Alds[128 * LDK];
    __shared__ __align__(16) __hip_bfloat16 Blds[128 * LDK];
    const int tid  = threadIdx.x;
    const int lane = tid & 63;
    const int w    = tid >> 6;
    const int wr   = w >> 1, wc = w & 1;
    const int fr   = lane & 15, fq = lane >> 4;
    const int m0 = blockIdx.y * 128, n0 = blockIdx.x * 128;

    const int srow = tid >> 1;          // 0..127
    const int scol = (tid & 1) * 16;    // 0 or 16
    const __hip_bfloat16* Ap = A  + (size_t)(m0 + srow) * K + scol;
    const __hip_bfloat16* Bp = Bt + (size_t)(n0 + srow) * K + scol;

    f32x4 acc[4][4] = {};

    for (int k0 = 0; k0 < K; k0 += 32) {
        const bf16x8 a0 = *reinterpret_cast<const bf16x8*>(Ap + k0);
        const bf16x8 a1 = *reinterpret_cast<const bf16x8*>(Ap + k0 + 8);
        const bf16x8 b0 = *reinterpret_cast<const bf16x8*>(Bp + k0);
        const bf16x8 b1 = *reinterpret_cast<const bf16x8*>(Bp + k0 + 8);
        __syncthreads();
        *reinterpret_cast<bf16x8*>(&Alds[srow * LDK + scol])     = a0;
        *reinterpret_cast<bf16x8*>(&Alds[srow * LDK + scol + 8]) = a1;
        *reinterpret_cast<bf16x8*>(&Blds[srow * LDK + scol])     = b0;
        *reinterpret_cast<bf16x8*>(&Blds[srow * LDK + scol + 8]) = b1;
        __syncthreads();
        bf16x8 af[4], bg[4];
        #pragma unroll
        for (int m = 0; m < 4; ++m)
            af[m] = *reinterpret_cast<const bf16x8*>(&Alds[(wr * 64 + m * 16 + fr) * LDK + fq * 8]);
        #pragma unroll
        for (int n = 0; n < 4; ++n)
            bg[n] = *reinterpret_cast<const bf16x8*>(&Blds[(wc * 64 + n * 16 + fr) * LDK + fq * 8]);
        #pragma unroll
        for (int m = 0; m < 4; ++m)
            #pragma unroll
            for (int n = 0; n < 4; ++n)
                acc[m][n] = MFMA16(af[m], bg[n], acc[m][n]);
    }

    #pragma unroll
    for (int n = 0; n < 4; ++n) {
        const int col = n0 + wc * 64 + n * 16 + fr;
        const float bv = bias[col];
        #pragma unroll
        for (int m = 0; m < 4; ++m) {
            #pragma unroll
            for (int i = 0; i < 4; ++i) {
                const int row = m0 + wr * 64 + m * 16 + fq * 4 + i;
                float v = acc[m][n][i] + bv;
                if (GELU) v = 0.5f * v * (1.0f + erff(v * 0.70710678118654752f));
                if (RESID) v += resid[(size_t)row * N + col];
                if (OUT_BF16)
                    reinterpret_cast<__hip_bfloat16*>(Cout)[(size_t)row * N + col] = __float2bfloat16(v);
                else
                    reinterpret_cast<float*>(Cout)[(size_t)row * N + col] = v;
            }
        }
    }
}

// ---------------------------------------------------------------------------
// Causal flash attention.
// qkv: [4096][3072] bf16 rows = b*2048+l; head h: q at col h*64, k at (16+h)*64,
// v at (32+h)*64. out: [4096][1024] bf16 (col h*64+c).
// Block = one 64-row q-tile of one (b,h). 4 waves, 16 q-rows each.
// ---------------------------------------------------------------------------
__global__ __launch_bounds__(256)
void attn_kernel(const __hip_bfloat16* __restrict__ qkv,
                 __hip_bfloat16* __restrict__ out)
{
    const int qt = blockIdx.x;   // 0..31
    const int h  = blockIdx.y;   // 0..15
    const int b  = blockIdx.z;   // 0..1
    const int q0 = qt * 64;
    const int tid  = threadIdx.x;
    const int lane = tid & 63;
    const int w    = tid >> 6;
    const int fr   = lane & 15, fq = lane >> 4;

    const __hip_bfloat16* base = qkv + (size_t)b * 2048 * 3072;

    __shared__ __align__(16) __hip_bfloat16 Vt[64 * 40];     // [hd][pos], pos-padded
    __shared__ __align__(16) __hip_bfloat16 Pl[4][16 * 40];  // per-wave [row][pos]

    bf16x8 qf[2];
    {
        const __hip_bfloat16* qp = base + (size_t)(q0 + w * 16 + fr) * 3072 + h * 64 + fq * 8;
        qf[0] = *reinterpret_cast<const bf16x8*>(qp);
        qf[1] = *reinterpret_cast<const bf16x8*>(qp + 32);
    }

    float m_run[4], l_run[4];
    f32x4 o[4] = {};
    int q_row[4];
    #pragma unroll
    for (int i = 0; i < 4; ++i) {
        m_run[i] = -1e30f; l_run[i] = 0.0f;
        q_row[i] = q0 + w * 16 + fq * 4 + i;
    }

    const int nkv = q0 + 64;
    for (int kv0 = 0; kv0 < nkv; kv0 += 32) {
        __syncthreads();  // prior iteration's Vt/Pl reads complete
        {   // stage V transposed: Vt[hd][pos_local]
            const int pl  = tid >> 3;         // 0..31
            const int hd0 = (tid & 7) * 8;    // 0,8,..,56
            const bf16x8 vv = *reinterpret_cast<const bf16x8*>(
                base + (size_t)(kv0 + pl) * 3072 + (32 + h) * 64 + hd0);
            #pragma unroll
            for (int j = 0; j < 8; ++j)
                Vt[(hd0 + j) * 40 + pl] = reinterpret_cast<const __hip_bfloat16*>(&vv)[j];
        }
        // S = (Q K^T) * 0.125, rows w*16.., cols kv0..kv0+31
        f32x4 s[2] = {};
        #pragma unroll
        for (int n = 0; n < 2; ++n) {
            const __hip_bfloat16* kp =
                base + (size_t)(kv0 + n * 16 + fr) * 3072 + (16 + h) * 64 + fq * 8;
            const bf16x8 k0f = *reinterpret_cast<const bf16x8*>(kp);
            const bf16x8 k1f = *reinterpret_cast<const bf16x8*>(kp + 32);
            s[n] = MFMA16(qf[0], k0f, s[n]);
            s[n] = MFMA16(qf[1], k1f, s[n]);
        }
        float pmax[4] = {-1e30f, -1e30f, -1e30f, -1e30f};
        #pragma unroll
        for (int n = 0; n < 2; ++n)
            #pragma unroll
            for (int i = 0; i < 4; ++i) {
                const int cpos = kv0 + n * 16 + fr;
                float sv = s[n][i] * 0.125f;
                sv = (cpos <= q_row[i]) ? sv : -1e30f;
                s[n][i] = sv;
                pmax[i] = fmaxf(pmax[i], sv);
            }
        #pragma unroll
        for (int off = 8; off >= 1; off >>= 1)
            #pragma unroll
            for (int i = 0; i < 4; ++i)
                pmax[i] = fmaxf(pmax[i], __shfl_xor(pmax[i], off, 16));
        float corr[4], rsum[4];
        #pragma unroll
        for (int i = 0; i < 4; ++i) {
            const float mnew = fmaxf(m_run[i], pmax[i]);
            corr[i] = expf(m_run[i] - mnew);
            m_run[i] = mnew;
            rsum[i] = 0.0f;
        }
        #pragma unroll
        for (int n = 0; n < 2; ++n)
            #pragma unroll
            for (int i = 0; i < 4; ++i) {
                const float p = expf(s[n][i] - m_run[i]);
                rsum[i] += p;
                Pl[w][(fq * 4 + i) * 40 + n * 16 + fr] = __float2bfloat16(p);
            }
        #pragma unroll
        for (int off = 8; off >= 1; off >>= 1)
            #pragma unroll
            for (int i = 0; i < 4; ++i)
                rsum[i] += __shfl_xor(rsum[i], off, 16);
        #pragma unroll
        for (int i = 0; i < 4; ++i)
            l_run[i] = l_run[i] * corr[i] + rsum[i];
        #pragma unroll
        for (int t = 0; t < 4; ++t)
            #pragma unroll
            for (int i = 0; i < 4; ++i)
                o[t][i] *= corr[i];
        __syncthreads();  // Vt + Pl writes visible
        const bf16x8 ap = *reinterpret_cast<const bf16x8*>(&Pl[w][fr * 40 + fq * 8]);
        #pragma unroll
        for (int t = 0; t < 4; ++t) {
            const bf16x8 bv = *reinterpret_cast<const bf16x8*>(&Vt[(t * 16 + fr) * 40 + fq * 8]);
            o[t] = MFMA16(ap, bv, o[t]);
        }
    }

    #pragma unroll
    for (int t = 0; t < 4; ++t)
        #pragma unroll
        for (int i = 0; i < 4; ++i) {
            const int row = q_row[i];
            out[(size_t)(b * 2048 + row) * 1024 + h * 64 + t * 16 + fr] =
                __float2bfloat16(o[t][i] / l_run[i]);
        }
}

// ---------------------------------------------------------------------------
extern "C" void kernel_launch(void* const* d_in, const int* in_sizes, int n_in,
                              void* d_out, int out_size, void* d_ws, size_t ws_size,
                              hipStream_t stream)
{
    (void)in_sizes; (void)n_in; (void)out_size; (void)ws_size;
    const float* x      = (const float*)d_in[0];
    // d_in[1] = mask: exactly causal tril by construction -> applied analytically
    const float* ln1_w  = (const float*)d_in[2];
    const float* ln1_b  = (const float*)d_in[3];
    const float* qkv_w  = (const float*)d_in[4];
    const float* qkv_b  = (const float*)d_in[5];
    const float* proj_w = (const float*)d_in[6];
    const float* proj_b = (const float*)d_in[7];
    const float* ln2_w  = (const float*)d_in[8];
    const float* ln2_b  = (const float*)d_in[9];
    const float* ffn_w1 = (const float*)d_in[10];
    const float* ffn_b1 = (const float*)d_in[11];
    const float* ffn_w2 = (const float*)d_in[12];
    const float* ffn_b2 = (const float*)d_in[13];
    float* outp = (float*)d_out;

    char* ws = (char*)d_ws;
    size_t off = 0;
    auto take = [&](size_t bytes) -> char* {
        char* p = ws + off;
        off += (bytes + 255) & ~(size_t)255;
        return p;
    };
    __hip_bfloat16* wqkv  = (__hip_bfloat16*)take((size_t)3072 * 1024 * 2);
    __hip_bfloat16* wproj = (__hip_bfloat16*)take((size_t)1024 * 1024 * 2);
    __hip_bfloat16* wff1  = (__hip_bfloat16*)take((size_t)4096 * 1024 * 2);
    __hip_bfloat16* wff2  = (__hip_bfloat16*)take((size_t)1024 * 4096 * 2);
    float*          hbuf  = (float*)take((size_t)4096 * 1024 * 4);
    __hip_bfloat16* xn    = (__hip_bfloat16*)take((size_t)4096 * 1024 * 2);
    __hip_bfloat16* qkvb  = (__hip_bfloat16*)take((size_t)4096 * 3072 * 2);
    __hip_bfloat16* attn  = (__hip_bfloat16*)take((size_t)4096 * 1024 * 2);
    __hip_bfloat16* ffn1  = qkvb;  // reuse qkv+attn regions (exactly 33.5 MB)

    // Weight transpose+convert: in [K][N] -> out [N][K] bf16
    transpose_to_bf16<<<dim3(3072 / 32, 1024 / 32), 256, 0, stream>>>(qkv_w, wqkv, 1024, 3072);
    transpose_to_bf16<<<dim3(1024 / 32, 1024 / 32), 256, 0, stream>>>(proj_w, wproj, 1024, 1024);
    transpose_to_bf16<<<dim3(4096 / 32, 1024 / 32), 256, 0, stream>>>(ffn_w1, wff1, 1024, 4096);
    transpose_to_bf16<<<dim3(1024 / 32, 4096 / 32), 256, 0, stream>>>(ffn_w2, wff2, 4096, 1024);

    // LN1
    ln_kernel<<<4096, 256, 0, stream>>>(x, ln1_w, ln1_b, xn);
    // QKV
    gemm_kernel<true, false, false><<<dim3(3072 / 128, 4096 / 128), 256, 0, stream>>>(
        xn, wqkv, qkv_b, nullptr, qkvb, 4096, 3072, 1024);
    // Attention
    attn_kernel<<<dim3(32, 16, 2), 256, 0, stream>>>(qkvb, attn);
    // proj + residual(x) -> h (fp32)
    gemm_kernel<false, false, true><<<dim3(1024 / 128, 4096 / 128), 256, 0, stream>>>(
        attn, wproj, proj_b, x, hbuf, 4096, 1024, 1024);
    // LN2 -> y (reuses xn)
    ln_kernel<<<4096, 256, 0, stream>>>(hbuf, ln2_w, ln2_b, xn);
    // FFN1 + gelu
    gemm_kernel<true, true, false><<<dim3(4096 / 128, 4096 / 128), 256, 0, stream>>>(
        xn, wff1, ffn_b1, nullptr, ffn1, 4096, 4096, 1024);
    // FFN2 + residual(h) -> out (fp32)
    gemm_kernel<false, false, true><<<dim3(1024 / 128, 4096 / 128), 256, 0, stream>>>(
        ffn1, wff2, ffn_b2, hbuf, outp, 4096, 1024, 4096);
}

// Round 2
// 483.937 us; speedup vs baseline: 1.0259x; 1.0259x over previous
//
#include <hip/hip_runtime.h>
#include <hip/hip_bf16.h>
#include <math.h>

typedef __attribute__((ext_vector_type(8))) short bf16x8;
typedef __attribute__((ext_vector_type(4))) float f32x4;

#define MFMA16(a, b, c) __builtin_amdgcn_mfma_f32_16x16x32_bf16((a), (b), (c), 0, 0, 0)

typedef const __attribute__((address_space(1))) void* gas_ptr;
typedef __attribute__((address_space(3))) void* las_ptr;

__device__ __forceinline__ unsigned pack_bf16(float a, float b) {
    unsigned ua = (unsigned)__bfloat16_as_ushort(__float2bfloat16(a));
    unsigned ub = (unsigned)__bfloat16_as_ushort(__float2bfloat16(b));
    return ua | (ub << 16);
}

// ---------------------------------------------------------------------------
// Transpose + fp32 -> bf16 convert:  in[K][N] f32  ->  out[N][K] bf16
// ---------------------------------------------------------------------------
__global__ __launch_bounds__(256)
void transpose_to_bf16(const float* __restrict__ in, __hip_bfloat16* __restrict__ out,
                       int K, int N)
{
    __shared__ float t[32][33];
    const int tx = threadIdx.x & 31, ty = threadIdx.x >> 5;
    const int n0 = blockIdx.x * 32, k0 = blockIdx.y * 32;
    #pragma unroll
    for (int j = 0; j < 32; j += 8)
        t[ty + j][tx] = in[(size_t)(k0 + ty + j) * N + n0 + tx];
    __syncthreads();
    #pragma unroll
    for (int j = 0; j < 32; j += 8)
        out[(size_t)(n0 + ty + j) * K + k0 + tx] = __float2bfloat16(t[tx][ty + j]);
}

// ---------------------------------------------------------------------------
// LayerNorm over D=1024, one block per row, fp32 in -> bf16 out
// ---------------------------------------------------------------------------
__global__ __launch_bounds__(256)
void ln_kernel(const float* __restrict__ in, const float* __restrict__ w,
               const float* __restrict__ b, __hip_bfloat16* __restrict__ out)
{
    const int row = blockIdx.x;
    const int tid = threadIdx.x;
    const float4 v = reinterpret_cast<const float4*>(in + (size_t)row * 1024)[tid];
    float s  = v.x + v.y + v.z + v.w;
    float s2 = v.x * v.x + v.y * v.y + v.z * v.z + v.w * v.w;
    #pragma unroll
    for (int off = 32; off > 0; off >>= 1) {
        s  += __shfl_down(s,  off);
        s2 += __shfl_down(s2, off);
    }
    __shared__ float red[8];
    const int wv = tid >> 6, ln = tid & 63;
    if (ln == 0) { red[wv] = s; red[4 + wv] = s2; }
    __syncthreads();
    s  = red[0] + red[1] + red[2] + red[3];
    s2 = red[4] + red[5] + red[6] + red[7];
    const float mu   = s * (1.0f / 1024.0f);
    const float var  = s2 * (1.0f / 1024.0f) - mu * mu;
    const float rstd = rsqrtf(var + 1e-5f);
    const float4 wv4 = reinterpret_cast<const float4*>(w)[tid];
    const float4 bv4 = reinterpret_cast<const float4*>(b)[tid];
    const size_t o = (size_t)row * 1024 + tid * 4;
    out[o + 0] = __float2bfloat16((v.x - mu) * rstd * wv4.x + bv4.x);
    out[o + 1] = __float2bfloat16((v.y - mu) * rstd * wv4.y + bv4.y);
    out[o + 2] = __float2bfloat16((v.z - mu) * rstd * wv4.z + bv4.z);
    out[o + 3] = __float2bfloat16((v.w - mu) * rstd * wv4.w + bv4.w);
}

// ---------------------------------------------------------------------------
// GEMM (m97 structure): C[M][N] = A[M][K] * Bt[N][K]^T + bias, fused epilogues.
// 128x128 tile, BK=32, 4 waves, global_load_lds width-16 staging, linear LDS.
// MODE 0: f32 out + f32 resid   MODE 1: bf16 out
// MODE 2: bf16 out + exact GELU MODE 3: QKV scatter (q|k -> C0 ld2048, V^T -> C1)
// ---------------------------------------------------------------------------
template<int MODE>
__global__ __launch_bounds__(256)
void gemm_kernel(const __hip_bfloat16* __restrict__ A,
                 const __hip_bfloat16* __restrict__ Bt,
                 const float* __restrict__ bias,
                 const float* __restrict__ resid,
                 void* __restrict__ C0, void* __restrict__ C1,
                 int M, int N, int K)
{
    __shared__ __align__(16) __hip_bfloat16 Alds[128 * 32];
    __shared__ __align__(16) __hip_bfloat16 Blds[128 * 32];
    const int tid  = threadIdx.x;
    const int lane = tid & 63;
    const int w    = tid >> 6;
    const int wr   = w >> 1, wc = w & 1;
    const int fr   = lane & 15, fq = lane >> 4;

    // XCD-aware swizzle (all grids used have nwg % 8 == 0)
    const int nwg = gridDim.x * gridDim.y;
    int flat = blockIdx.y * gridDim.x + blockIdx.x;
    flat = (flat & 7) * (nwg >> 3) + (flat >> 3);
    const int bx = flat % gridDim.x, by = flat / gridDim.x;
    const int m0 = by * 128, n0 = bx * 128;

    // staging: each wave covers 32 rows of A and 32 rows of B per k-step,
    // 2 issues each (16 rows / issue; lane -> row (lane>>2), col (lane&3)*8).
    const int srow = lane >> 2;
    const int scol = (lane & 3) * 8;
    const __hip_bfloat16* Ag = A  + (size_t)(m0 + w * 32 + srow) * K + scol;
    const __hip_bfloat16* Bg = Bt + (size_t)(n0 + w * 32 + srow) * K + scol;
    __hip_bfloat16* Al = &Alds[(w * 32) * 32];
    __hip_bfloat16* Bl = &Blds[(w * 32) * 32];

    f32x4 acc[4][4] = {};

    for (int k0 = 0; k0 < K; k0 += 32) {
        __syncthreads();  // previous tile fully consumed
        __builtin_amdgcn_global_load_lds((gas_ptr)(const void*)(Ag + k0),
                                         (las_ptr)(void*)Al, 16, 0, 0);
        __builtin_amdgcn_global_load_lds((gas_ptr)(const void*)(Ag + (size_t)16 * K + k0),
                                         (las_ptr)(void*)(Al + 16 * 32), 16, 0, 0);
        __builtin_amdgcn_global_load_lds((gas_ptr)(const void*)(Bg + k0),
                                         (las_ptr)(void*)Bl, 16, 0, 0);
        __builtin_amdgcn_global_load_lds((gas_ptr)(const void*)(Bg + (size_t)16 * K + k0),
                                         (las_ptr)(void*)(Bl + 16 * 32), 16, 0, 0);
        __syncthreads();  // waits vmcnt(0): tile resident
        bf16x8 af[4], bg[4];
        #pragma unroll
        for (int m = 0; m < 4; ++m)
            af[m] = *reinterpret_cast<const bf16x8*>(&Alds[(wr * 64 + m * 16 + fr) * 32 + fq * 8]);
        #pragma unroll
        for (int n = 0; n < 4; ++n)
            bg[n] = *reinterpret_cast<const bf16x8*>(&Blds[(wc * 64 + n * 16 + fr) * 32 + fq * 8]);
        #pragma unroll
        for (int m = 0; m < 4; ++m)
            #pragma unroll
            for (int n = 0; n < 4; ++n)
                acc[m][n] = MFMA16(af[m], bg[n], acc[m][n]);
    }

    #pragma unroll
    for (int n = 0; n < 4; ++n) {
        const int col = n0 + wc * 64 + n * 16 + fr;
        const float bv = bias[col];
        #pragma unroll
        for (int m = 0; m < 4; ++m) {
            #pragma unroll
            for (int i = 0; i < 4; ++i) {
                const int row = m0 + wr * 64 + m * 16 + fq * 4 + i;
                float v = acc[m][n][i] + bv;
                if (MODE == 2) v = 0.5f * v * (1.0f + erff(v * 0.70710678118654752f));
                if (MODE == 0) {
                    v += resid[(size_t)row * N + col];
                    reinterpret_cast<float*>(C0)[(size_t)row * N + col] = v;
                } else if (MODE == 3) {
                    if (col < 2048) {
                        reinterpret_cast<__hip_bfloat16*>(C0)[((size_t)row << 11) + col] =
                            __float2bfloat16(v);
                    } else {
                        const int b = row >> 11, l = row & 2047;
                        const int hc = col - 2048;  // h*64 + c
                        reinterpret_cast<__hip_bfloat16*>(C1)[((size_t)(b * 1024 + hc) << 11) + l] =
                            __float2bfloat16(v);
                    }
                } else {
                    reinterpret_cast<__hip_bfloat16*>(C0)[(size_t)row * N + col] =
                        __float2bfloat16(v);
                }
            }
        }
    }
}

// ---------------------------------------------------------------------------
// Causal flash attention, no LDS, no barriers.
// qk : [4096][2048] bf16 (q at h*64, k at 1024+h*64), rows = b*2048+l
// Vt : [b][h][64][2048] bf16 (V transposed per head)
// out: [4096][1024] bf16
// Block = 64 q-rows of one (b,h); 4 independent waves x 16 q-rows; KVBLK=64.
// Swapped QK^T: S^T = mfma(K,Q) -> lane owns P row for q = lane&15.
// ---------------------------------------------------------------------------
__global__ __launch_bounds__(256)
void attn_kernel(const __hip_bfloat16* __restrict__ qk,
                 const __hip_bfloat16* __restrict__ Vt,
                 __hip_bfloat16* __restrict__ out)
{
    // XCD swizzle: 1024 blocks -> each XCD gets 4 consecutive (b,h) panels
    int flat = blockIdx.x;
    flat = (flat & 7) * 128 + (flat >> 3);
    const int qt = flat & 31;
    const int h  = (flat >> 5) & 15;
    const int b  = flat >> 9;
    const int q0 = qt * 64;

    const int lane = threadIdx.x & 63;
    const int w    = threadIdx.x >> 6;
    const int fr   = lane & 15, fq = lane >> 4;
    const int qrow = q0 + w * 16 + fr;              // softmax-lane q row

    // Q as B-fragments (col = q = fr, k = d)
    bf16x8 qf[2];
    {
        const __hip_bfloat16* qp = qk + ((size_t)(b * 2048 + qrow) << 11) + h * 64 + fq * 8;
        qf[0] = *reinterpret_cast<const bf16x8*>(qp);
        qf[1] = *reinterpret_cast<const bf16x8*>(qp + 32);
    }

    const float SC = 0.125f * 1.44269504088896f;  // scale folded with log2(e)
    float m_run = -1e30f, l_run = 0.0f;
    f32x4 o[4] = {};

    for (int kv0 = 0; kv0 < q0 + 64; kv0 += 64) {
        // ---- S^T = K * Q^T : 4 kv sub-tiles of 16 ----
        f32x4 s[4] = {};
        const __hip_bfloat16* kb =
            qk + ((size_t)(b * 2048 + kv0 + fr) << 11) + 1024 + h * 64 + fq * 8;
        #pragma unroll
        for (int n = 0; n < 4; ++n) {
            const bf16x8 k0f = *reinterpret_cast<const bf16x8*>(kb + ((size_t)(n * 16) << 11));
            const bf16x8 k1f = *reinterpret_cast<const bf16x8*>(kb + ((size_t)(n * 16) << 11) + 32);
            s[n] = MFMA16(k0f, qf[0], s[n]);
            s[n] = MFMA16(k1f, qf[1], s[n]);
        }
        // ---- scale + causal mask; lane holds S^T[kv0+n*16+fq*4+i][qrow] ----
        float pm = -1e30f;
        #pragma unroll
        for (int n = 0; n < 4; ++n)
            #pragma unroll
            for (int i = 0; i < 4; ++i) {
                const int kvp = kv0 + n * 16 + fq * 4 + i;
                float sv = s[n][i] * SC;
                sv = (kvp <= qrow) ? sv : -1e30f;
                s[n][i] = sv;
                pm = fmaxf(pm, sv);
            }
        pm = fmaxf(pm, __shfl_xor(pm, 16));
        pm = fmaxf(pm, __shfl_xor(pm, 32));
        const float mnew = fmaxf(m_run, pm);
        const float corr = exp2f(m_run - mnew);
        m_run = mnew;
        // ---- P = exp2(S - m), packed to bf16 pairs ----
        float rs = 0.0f;
        unsigned pk[8];
        #pragma unroll
        for (int n = 0; n < 4; ++n) {
            const float p0 = exp2f(s[n][0] - mnew);
            const float p1 = exp2f(s[n][1] - mnew);
            const float p2 = exp2f(s[n][2] - mnew);
            const float p3 = exp2f(s[n][3] - mnew);
            rs += (p0 + p1) + (p2 + p3);
            pk[n * 2 + 0] = pack_bf16(p0, p1);
            pk[n * 2 + 1] = pack_bf16(p2, p3);
        }
        rs += __shfl_xor(rs, 16);
        rs += __shfl_xor(rs, 32);
        l_run = l_run * corr + rs;
        // ---- rescale O (O-rows are q = q0+w*16+fq*4+i) ----
        #pragma unroll
        for (int i = 0; i < 4; ++i) {
            const float ci = __shfl(corr, fq * 4 + i);
            o[0][i] *= ci; o[1][i] *= ci; o[2][i] *= ci; o[3][i] *= ci;
        }
        // ---- relayout P (S^T C-layout) -> PV A-fragments, 2 kv halves ----
        // target reg r: kv = fq*8+2r+{0,1}; src lane fq_s = 2(fq&1)+(r>>1);
        // src packed reg = 2(fq>>1)+(r&1) -> select hi/lo by (fq&2).
        unsigned ar0[4], ar1[4];
        #pragma unroll
        for (int r = 0; r < 4; ++r) {
            const int sl = fr + ((2 * (fq & 1) + (r >> 1)) << 4);
            const unsigned lo0 = __shfl(pk[0 + (r & 1)], sl);
            const unsigned hi0 = __shfl(pk[2 + (r & 1)], sl);
            const unsigned lo1 = __shfl(pk[4 + (r & 1)], sl);
            const unsigned hi1 = __shfl(pk[6 + (r & 1)], sl);
            ar0[r] = (fq & 2) ? hi0 : lo0;
            ar1[r] = (fq & 2) ? hi1 : lo1;
        }
        const bf16x8 pa0 = *reinterpret_cast<const bf16x8*>(ar0);
        const bf16x8 pa1 = *reinterpret_cast<const bf16x8*>(ar1);
        // ---- O += P V : V^T fragments straight from global ----
        const __hip_bfloat16* vb =
            Vt + ((size_t)(b * 1024 + h * 64) << 11) + kv0 + fq * 8;
        #pragma unroll
        for (int t = 0; t < 4; ++t) {
            const bf16x8 v0 = *reinterpret_cast<const bf16x8*>(vb + ((size_t)(t * 16 + fr) << 11));
            const bf16x8 v1 = *reinterpret_cast<const bf16x8*>(vb + ((size_t)(t * 16 + fr) << 11) + 32);
            o[t] = MFMA16(pa0, v0, o[t]);
            o[t] = MFMA16(pa1, v1, o[t]);
        }
    }

    // ---- normalize + write ----
    #pragma unroll
    for (int i = 0; i < 4; ++i) {
        const float li  = __shfl(l_run, fq * 4 + i);
        const float inv = 1.0f / li;
        const int row = q0 + w * 16 + fq * 4 + i;
        #pragma unroll
        for (int t = 0; t < 4; ++t)
            out[(size_t)(b * 2048 + row) * 1024 + h * 64 + t * 16 + fr] =
                __float2bfloat16(o[t][i] * inv);
    }
}

// ---------------------------------------------------------------------------
extern "C" void kernel_launch(void* const* d_in, const int* in_sizes, int n_in,
                              void* d_out, int out_size, void* d_ws, size_t ws_size,
                              hipStream_t stream)
{
    (void)in_sizes; (void)n_in; (void)out_size; (void)ws_size;
    const float* x      = (const float*)d_in[0];
    const float* ln1_w  = (const float*)d_in[2];
    const float* ln1_b  = (const float*)d_in[3];
    const float* qkv_w  = (const float*)d_in[4];
    const float* qkv_b  = (const float*)d_in[5];
    const float* proj_w = (const float*)d_in[6];
    const float* proj_b = (const float*)d_in[7];
    const float* ln2_w  = (const float*)d_in[8];
    const float* ln2_b  = (const float*)d_in[9];
    const float* ffn_w1 = (const float*)d_in[10];
    const float* ffn_b1 = (const float*)d_in[11];
    const float* ffn_w2 = (const float*)d_in[12];
    const float* ffn_b2 = (const float*)d_in[13];
    float* outp = (float*)d_out;

    char* ws = (char*)d_ws;
    size_t off = 0;
    auto take = [&](size_t bytes) -> char* {
        char* p = ws + off;
        off += (bytes + 255) & ~(size_t)255;
        return p;
    };
    __hip_bfloat16* wqkv  = (__hip_bfloat16*)take((size_t)3072 * 1024 * 2);  // 6 MB
    __hip_bfloat16* wproj = (__hip_bfloat16*)take((size_t)1024 * 1024 * 2);  // 2 MB
    __hip_bfloat16* wff1  = (__hip_bfloat16*)take((size_t)4096 * 1024 * 2);  // 8 MB
    __hip_bfloat16* wff2  = (__hip_bfloat16*)take((size_t)1024 * 4096 * 2);  // 8 MB
    float*          hbuf  = (float*)take((size_t)4096 * 1024 * 4);           // 16 MB
    __hip_bfloat16* xn    = (__hip_bfloat16*)take((size_t)4096 * 1024 * 2);  // 8 MB
    __hip_bfloat16* qkb   = (__hip_bfloat16*)take((size_t)4096 * 2048 * 2);  // 16 MB
    __hip_bfloat16* Vt    = (__hip_bfloat16*)take((size_t)2048 * 2048 * 2);  // 8 MB
    __hip_bfloat16* attn  = (__hip_bfloat16*)take((size_t)4096 * 1024 * 2);  // 8 MB
    // FFN1 output (32 MB) reuses qkb+Vt+attn (contiguous, all dead by then)
    __hip_bfloat16* ffn1  = qkb;

    transpose_to_bf16<<<dim3(3072 / 32, 1024 / 32), 256, 0, stream>>>(qkv_w, wqkv, 1024, 3072);
    transpose_to_bf16<<<dim3(1024 / 32, 1024 / 32), 256, 0, stream>>>(proj_w, wproj, 1024, 1024);
    transpose_to_bf16<<<dim3(4096 / 32, 1024 / 32), 256, 0, stream>>>(ffn_w1, wff1, 1024, 4096);
    transpose_to_bf16<<<dim3(1024 / 32, 4096 / 32), 256, 0, stream>>>(ffn_w2, wff2, 4096, 1024);

    // LN1
    ln_kernel<<<4096, 256, 0, stream>>>(x, ln1_w, ln1_b, xn);
    // QKV with q|k / V^T scatter
    gemm_kernel<3><<<dim3(24, 32), 256, 0, stream>>>(
        xn, wqkv, qkv_b, nullptr, qkb, Vt, 4096, 3072, 1024);
    // Attention
    attn_kernel<<<1024, 256, 0, stream>>>(qkb, Vt, attn);
    // proj + residual(x) -> h (fp32)
    gemm_kernel<0><<<dim3(8, 32), 256, 0, stream>>>(
        attn, wproj, proj_b, x, hbuf, nullptr, 4096, 1024, 1024);
    // LN2 -> y
    ln_kernel<<<4096, 256, 0, stream>>>(hbuf, ln2_w, ln2_b, xn);
    // FFN1 + exact GELU
    gemm_kernel<2><<<dim3(32, 32), 256, 0, stream>>>(
        xn, wff1, ffn_b1, nullptr, ffn1, nullptr, 4096, 4096, 1024);
    // FFN2 + residual(h) -> out (fp32)
    gemm_kernel<0><<<dim3(8, 32), 256, 0, stream>>>(
        ffn1, wff2, ffn_b2, hbuf, outp, nullptr, 4096, 1024, 4096);
}

// Round 3
// 315.722 us; speedup vs baseline: 1.5726x; 1.5328x over previous
//
#include <hip/hip_runtime.h>
#include <hip/hip_bf16.h>
#include <math.h>

typedef __attribute__((ext_vector_type(8))) short bf16x8;
typedef __attribute__((ext_vector_type(4))) float f32x4;
typedef __attribute__((ext_vector_type(4))) unsigned u32x4;

#define MFMA16(a, b, c) __builtin_amdgcn_mfma_f32_16x16x32_bf16((a), (b), (c), 0, 0, 0)

typedef const __attribute__((address_space(1))) void* gas_ptr;
typedef __attribute__((address_space(3))) void* las_ptr;

__device__ __forceinline__ unsigned pack_bf16(float a, float b) {
    unsigned ua = (unsigned)__bfloat16_as_ushort(__float2bfloat16(a));
    unsigned ub = (unsigned)__bfloat16_as_ushort(__float2bfloat16(b));
    return ua | (ub << 16);
}

// ---------------------------------------------------------------------------
// Transpose + fp32 -> bf16 convert:  in[K][N] f32  ->  out[N][K] bf16
// ---------------------------------------------------------------------------
__global__ __launch_bounds__(256)
void transpose_to_bf16(const float* __restrict__ in, __hip_bfloat16* __restrict__ out,
                       int K, int N)
{
    __shared__ float t[32][33];
    const int tx = threadIdx.x & 31, ty = threadIdx.x >> 5;
    const int n0 = blockIdx.x * 32, k0 = blockIdx.y * 32;
    #pragma unroll
    for (int j = 0; j < 32; j += 8)
        t[ty + j][tx] = in[(size_t)(k0 + ty + j) * N + n0 + tx];
    __syncthreads();
    #pragma unroll
    for (int j = 0; j < 32; j += 8)
        out[(size_t)(n0 + ty + j) * K + k0 + tx] = __float2bfloat16(t[tx][ty + j]);
}

// ---------------------------------------------------------------------------
// LayerNorm over D=1024, one block per row, fp32 in -> bf16 out
// ---------------------------------------------------------------------------
__global__ __launch_bounds__(256)
void ln_kernel(const float* __restrict__ in, const float* __restrict__ w,
               const float* __restrict__ b, __hip_bfloat16* __restrict__ out)
{
    const int row = blockIdx.x;
    const int tid = threadIdx.x;
    const float4 v = reinterpret_cast<const float4*>(in + (size_t)row * 1024)[tid];
    float s  = v.x + v.y + v.z + v.w;
    float s2 = v.x * v.x + v.y * v.y + v.z * v.z + v.w * v.w;
    #pragma unroll
    for (int off = 32; off > 0; off >>= 1) {
        s  += __shfl_down(s,  off);
        s2 += __shfl_down(s2, off);
    }
    __shared__ float red[8];
    const int wv = tid >> 6, ln = tid & 63;
    if (ln == 0) { red[wv] = s; red[4 + wv] = s2; }
    __syncthreads();
    s  = red[0] + red[1] + red[2] + red[3];
    s2 = red[4] + red[5] + red[6] + red[7];
    const float mu   = s * (1.0f / 1024.0f);
    const float var  = s2 * (1.0f / 1024.0f) - mu * mu;
    const float rstd = rsqrtf(var + 1e-5f);
    const float4 wv4 = reinterpret_cast<const float4*>(w)[tid];
    const float4 bv4 = reinterpret_cast<const float4*>(b)[tid];
    const size_t o = (size_t)row * 1024 + tid * 4;
    out[o + 0] = __float2bfloat16((v.x - mu) * rstd * wv4.x + bv4.x);
    out[o + 1] = __float2bfloat16((v.y - mu) * rstd * wv4.y + bv4.y);
    out[o + 2] = __float2bfloat16((v.z - mu) * rstd * wv4.z + bv4.z);
    out[o + 3] = __float2bfloat16((v.w - mu) * rstd * wv4.w + bv4.w);
}

// ---------------------------------------------------------------------------
// GEMM (m97 structure): C[M][N] = A[M][K] * Bt[N][K]^T + bias, fused epilogues.
// 128x128 tile, BK=32, 4 waves, global_load_lds width-16 staging, linear LDS.
// MODE 0: f32 out + f32 resid   MODE 1: bf16 out
// MODE 2: bf16 out + exact GELU MODE 3: QKV scatter (q|k -> C0 ld2048, V^T -> C1)
// ---------------------------------------------------------------------------
template<int MODE>
__global__ __launch_bounds__(256)
void gemm_kernel(const __hip_bfloat16* __restrict__ A,
                 const __hip_bfloat16* __restrict__ Bt,
                 const float* __restrict__ bias,
                 const float* __restrict__ resid,
                 void* __restrict__ C0, void* __restrict__ C1,
                 int M, int N, int K)
{
    __shared__ __align__(16) __hip_bfloat16 Alds[128 * 32];
    __shared__ __align__(16) __hip_bfloat16 Blds[128 * 32];
    const int tid  = threadIdx.x;
    const int lane = tid & 63;
    const int w    = tid >> 6;
    const int wr   = w >> 1, wc = w & 1;
    const int fr   = lane & 15, fq = lane >> 4;

    // XCD-aware swizzle (all grids used have nwg % 8 == 0)
    const int nwg = gridDim.x * gridDim.y;
    int flat = blockIdx.y * gridDim.x + blockIdx.x;
    flat = (flat & 7) * (nwg >> 3) + (flat >> 3);
    const int bx = flat % gridDim.x, by = flat / gridDim.x;
    const int m0 = by * 128, n0 = bx * 128;

    const int srow = lane >> 2;
    const int scol = (lane & 3) * 8;
    const __hip_bfloat16* Ag = A  + (size_t)(m0 + w * 32 + srow) * K + scol;
    const __hip_bfloat16* Bg = Bt + (size_t)(n0 + w * 32 + srow) * K + scol;
    __hip_bfloat16* Al = &Alds[(w * 32) * 32];
    __hip_bfloat16* Bl = &Blds[(w * 32) * 32];

    f32x4 acc[4][4] = {};

    for (int k0 = 0; k0 < K; k0 += 32) {
        __syncthreads();
        __builtin_amdgcn_global_load_lds((gas_ptr)(const void*)(Ag + k0),
                                         (las_ptr)(void*)Al, 16, 0, 0);
        __builtin_amdgcn_global_load_lds((gas_ptr)(const void*)(Ag + (size_t)16 * K + k0),
                                         (las_ptr)(void*)(Al + 16 * 32), 16, 0, 0);
        __builtin_amdgcn_global_load_lds((gas_ptr)(const void*)(Bg + k0),
                                         (las_ptr)(void*)Bl, 16, 0, 0);
        __builtin_amdgcn_global_load_lds((gas_ptr)(const void*)(Bg + (size_t)16 * K + k0),
                                         (las_ptr)(void*)(Bl + 16 * 32), 16, 0, 0);
        __syncthreads();
        bf16x8 af[4], bg[4];
        #pragma unroll
        for (int m = 0; m < 4; ++m)
            af[m] = *reinterpret_cast<const bf16x8*>(&Alds[(wr * 64 + m * 16 + fr) * 32 + fq * 8]);
        #pragma unroll
        for (int n = 0; n < 4; ++n)
            bg[n] = *reinterpret_cast<const bf16x8*>(&Blds[(wc * 64 + n * 16 + fr) * 32 + fq * 8]);
        #pragma unroll
        for (int m = 0; m < 4; ++m)
            #pragma unroll
            for (int n = 0; n < 4; ++n)
                acc[m][n] = MFMA16(af[m], bg[n], acc[m][n]);
    }

    #pragma unroll
    for (int n = 0; n < 4; ++n) {
        const int col = n0 + wc * 64 + n * 16 + fr;
        const float bv = bias[col];
        #pragma unroll
        for (int m = 0; m < 4; ++m) {
            #pragma unroll
            for (int i = 0; i < 4; ++i) {
                const int row = m0 + wr * 64 + m * 16 + fq * 4 + i;
                float v = acc[m][n][i] + bv;
                if (MODE == 2) v = 0.5f * v * (1.0f + erff(v * 0.70710678118654752f));
                if (MODE == 0) {
                    v += resid[(size_t)row * N + col];
                    reinterpret_cast<float*>(C0)[(size_t)row * N + col] = v;
                } else if (MODE == 3) {
                    if (col < 2048) {
                        reinterpret_cast<__hip_bfloat16*>(C0)[((size_t)row << 11) + col] =
                            __float2bfloat16(v);
                    } else {
                        const int b = row >> 11, l = row & 2047;
                        const int hc = col - 2048;  // h*64 + c
                        reinterpret_cast<__hip_bfloat16*>(C1)[((size_t)(b * 1024 + hc) << 11) + l] =
                            __float2bfloat16(v);
                    }
                } else {
                    reinterpret_cast<__hip_bfloat16*>(C0)[(size_t)row * N + col] =
                        __float2bfloat16(v);
                }
            }
        }
    }
}

// ---------------------------------------------------------------------------
// Causal flash attention, LDS double-buffered K/V tiles shared by 4 waves.
// qk : [4096][2048] bf16 (q at h*64, k at 1024+h*64), rows = b*2048+l
// Vt : [b][h][64][2048] bf16 (V transposed per head)
// out: [4096][1024] bf16
// Block = 64 q-rows of one (b,h); wave w owns rows w*16..+16. KV tile = 64.
// K/V tiles staged via global_load_lds with XOR-swizzle (pre-swizzled global
// source column, swizzled ds_read). Longest-first + XCD-panel dispatch.
// ---------------------------------------------------------------------------
__global__ __launch_bounds__(256)
void attn_kernel(const __hip_bfloat16* __restrict__ qk,
                 const __hip_bfloat16* __restrict__ Vt,
                 __hip_bfloat16* __restrict__ out)
{
    // dispatch: xcd = bid&7 keeps 4 (b,h) panels per XCD; qt descending so the
    // longest (32-tile) blocks launch first and short blocks backfill the tail
    const int bid  = blockIdx.x;            // 0..1023
    const int xcd  = bid & 7;
    const int rank = bid >> 3;               // 0..127
    const int panel = xcd * 4 + (rank & 3);  // 0..31
    const int qt   = 31 - (rank >> 2);       // 31..0
    const int h = panel & 15, b = panel >> 4;
    const int q0 = qt * 64;

    const int lane = threadIdx.x & 63;
    const int w    = threadIdx.x >> 6;
    const int fr   = lane & 15, fq = lane >> 4;
    const int qrow = q0 + w * 16 + fr;       // softmax-lane q row

    __shared__ __align__(16) __hip_bfloat16 Klds[2][64 * 64];
    __shared__ __align__(16) __hip_bfloat16 Vlds[2][64 * 64];

    // Q as B-fragments (col = q = fr, k = d)
    bf16x8 qf[2];
    {
        const __hip_bfloat16* qp = qk + ((size_t)(b * 2048 + qrow) << 11) + h * 64 + fq * 8;
        qf[0] = *reinterpret_cast<const bf16x8*>(qp);
        qf[1] = *reinterpret_cast<const bf16x8*>(qp + 32);
    }

    // staging source pointers (pre-swizzled column so linear LDS dest holds
    // the XOR-swizzled layout); lane -> local row (lane>>3) + 16B chunk (lane&7)
    const int srow8 = lane >> 3;
    const int sc    = lane & 7;
    const __hip_bfloat16* Kg[2];
    const __hip_bfloat16* Vg[2];
    #pragma unroll
    for (int j = 0; j < 2; ++j) {
        const int r = w * 16 + j * 8 + srow8;          // local kv row / d row
        const int csw = (sc ^ (r & 7)) * 8;            // inverse-swizzled col (elems)
        Kg[j] = qk + ((size_t)(b * 2048 + r) << 11) + 1024 + h * 64 + csw;
        Vg[j] = Vt + ((size_t)(b * 1024 + h * 64 + r) << 11) + csw;
    }

    auto stage = [&](int kv0, int bufi) {
        __hip_bfloat16* KL = &Klds[bufi][0];
        __hip_bfloat16* VL = &Vlds[bufi][0];
        #pragma unroll
        for (int j = 0; j < 2; ++j) {
            __builtin_amdgcn_global_load_lds(
                (gas_ptr)(const void*)(Kg[j] + ((size_t)kv0 << 11)),
                (las_ptr)(void*)&KL[(w * 16 + j * 8) * 64], 16, 0, 0);
            __builtin_amdgcn_global_load_lds(
                (gas_ptr)(const void*)(Vg[j] + kv0),
                (las_ptr)(void*)&VL[(w * 16 + j * 8) * 64], 16, 0, 0);
        }
    };

    const float SC = 0.125f * 1.44269504088896f;  // scale folded with log2(e)
    float m_run = -1e30f, l_run = 0.0f;
    f32x4 o[4] = {};

    const int ntiles = qt + 1;
    stage(0, 0);
    int cur = 0;

    for (int t = 0; t < ntiles; ++t) {
        const int kv0 = t << 6;
        __syncthreads();                       // tile t resident; prev reads done
        if (t + 1 < ntiles) stage((t + 1) << 6, cur ^ 1);

        const __hip_bfloat16* Kl = &Klds[cur][0];
        const __hip_bfloat16* Vl = &Vlds[cur][0];

        // ---- S^T = K * Q^T (A=K rows from LDS, swizzled read) ----
        f32x4 s[4] = {};
        #pragma unroll
        for (int n = 0; n < 4; ++n) {
            const int row = n * 16 + fr;
            const int sw = (row & 7) << 3;
            const bf16x8 k0 = *reinterpret_cast<const bf16x8*>(&Kl[row * 64 + ((fq * 8) ^ sw)]);
            const bf16x8 k1 = *reinterpret_cast<const bf16x8*>(&Kl[row * 64 + ((fq * 8 + 32) ^ sw)]);
            s[n] = MFMA16(k0, qf[0], s[n]);
            s[n] = MFMA16(k1, qf[1], s[n]);
        }

        // ---- scale (+ causal mask only on diagonal tile) + row max ----
        float pm = -1e30f;
        if (t == ntiles - 1) {
            #pragma unroll
            for (int n = 0; n < 4; ++n)
                #pragma unroll
                for (int i = 0; i < 4; ++i) {
                    const int kvp = kv0 + n * 16 + fq * 4 + i;
                    float sv = s[n][i] * SC;
                    sv = (kvp <= qrow) ? sv : -1e30f;
                    s[n][i] = sv;
                    pm = fmaxf(pm, sv);
                }
        } else {
            #pragma unroll
            for (int n = 0; n < 4; ++n)
                #pragma unroll
                for (int i = 0; i < 4; ++i) {
                    const float sv = s[n][i] * SC;
                    s[n][i] = sv;
                    pm = fmaxf(pm, sv);
                }
        }
        pm = fmaxf(pm, __shfl_xor(pm, 16));
        pm = fmaxf(pm, __shfl_xor(pm, 32));
        const float mnew = fmaxf(m_run, pm);
        const float corr = exp2f(m_run - mnew);
        m_run = mnew;

        // ---- P = exp2(S - m), packed bf16 pairs ----
        float rs = 0.0f;
        unsigned pk[8];
        #pragma unroll
        for (int n = 0; n < 4; ++n) {
            const float p0 = exp2f(s[n][0] - mnew);
            const float p1 = exp2f(s[n][1] - mnew);
            const float p2 = exp2f(s[n][2] - mnew);
            const float p3 = exp2f(s[n][3] - mnew);
            rs += (p0 + p1) + (p2 + p3);
            pk[n * 2 + 0] = pack_bf16(p0, p1);
            pk[n * 2 + 1] = pack_bf16(p2, p3);
        }
        rs += __shfl_xor(rs, 16);
        rs += __shfl_xor(rs, 32);
        l_run = l_run * corr + rs;

        // ---- rescale O ----
        #pragma unroll
        for (int i = 0; i < 4; ++i) {
            const float ci = __shfl(corr, fq * 4 + i);
            o[0][i] *= ci; o[1][i] *= ci; o[2][i] *= ci; o[3][i] *= ci;
        }

        // ---- relayout P (S^T C-layout) -> PV A-fragments ----
        u32x4 A0, A1;
        #pragma unroll
        for (int r = 0; r < 4; ++r) {
            const int sl = fr + ((2 * (fq & 1) + (r >> 1)) << 4);
            const unsigned lo0 = __shfl(pk[0 + (r & 1)], sl);
            const unsigned hi0 = __shfl(pk[2 + (r & 1)], sl);
            const unsigned lo1 = __shfl(pk[4 + (r & 1)], sl);
            const unsigned hi1 = __shfl(pk[6 + (r & 1)], sl);
            A0[r] = (fq & 2) ? hi0 : lo0;
            A1[r] = (fq & 2) ? hi1 : lo1;
        }
        const bf16x8 pa0 = __builtin_bit_cast(bf16x8, A0);
        const bf16x8 pa1 = __builtin_bit_cast(bf16x8, A1);

        // ---- O += P V (B = V^T rows from LDS, swizzled read) ----
        #pragma unroll
        for (int tt = 0; tt < 4; ++tt) {
            const int row = tt * 16 + fr;
            const int sw = (row & 7) << 3;
            const bf16x8 v0 = *reinterpret_cast<const bf16x8*>(&Vl[row * 64 + ((fq * 8) ^ sw)]);
            const bf16x8 v1 = *reinterpret_cast<const bf16x8*>(&Vl[row * 64 + ((fq * 8 + 32) ^ sw)]);
            o[tt] = MFMA16(pa0, v0, o[tt]);
            o[tt] = MFMA16(pa1, v1, o[tt]);
        }
        cur ^= 1;
    }

    // ---- normalize + write ----
    #pragma unroll
    for (int i = 0; i < 4; ++i) {
        const float li  = __shfl(l_run, fq * 4 + i);
        const float inv = 1.0f / li;
        const int row = q0 + w * 16 + fq * 4 + i;
        #pragma unroll
        for (int tt = 0; tt < 4; ++tt)
            out[(size_t)(b * 2048 + row) * 1024 + h * 64 + tt * 16 + fr] =
                __float2bfloat16(o[tt][i] * inv);
    }
}

// ---------------------------------------------------------------------------
extern "C" void kernel_launch(void* const* d_in, const int* in_sizes, int n_in,
                              void* d_out, int out_size, void* d_ws, size_t ws_size,
                              hipStream_t stream)
{
    (void)in_sizes; (void)n_in; (void)out_size; (void)ws_size;
    const float* x      = (const float*)d_in[0];
    const float* ln1_w  = (const float*)d_in[2];
    const float* ln1_b  = (const float*)d_in[3];
    const float* qkv_w  = (const float*)d_in[4];
    const float* qkv_b  = (const float*)d_in[5];
    const float* proj_w = (const float*)d_in[6];
    const float* proj_b = (const float*)d_in[7];
    const float* ln2_w  = (const float*)d_in[8];
    const float* ln2_b  = (const float*)d_in[9];
    const float* ffn_w1 = (const float*)d_in[10];
    const float* ffn_b1 = (const float*)d_in[11];
    const float* ffn_w2 = (const float*)d_in[12];
    const float* ffn_b2 = (const float*)d_in[13];
    float* outp = (float*)d_out;

    char* ws = (char*)d_ws;
    size_t off = 0;
    auto take = [&](size_t bytes) -> char* {
        char* p = ws + off;
        off += (bytes + 255) & ~(size_t)255;
        return p;
    };
    __hip_bfloat16* wqkv  = (__hip_bfloat16*)take((size_t)3072 * 1024 * 2);  // 6 MB
    __hip_bfloat16* wproj = (__hip_bfloat16*)take((size_t)1024 * 1024 * 2);  // 2 MB
    __hip_bfloat16* wff1  = (__hip_bfloat16*)take((size_t)4096 * 1024 * 2);  // 8 MB
    __hip_bfloat16* wff2  = (__hip_bfloat16*)take((size_t)1024 * 4096 * 2);  // 8 MB
    float*          hbuf  = (float*)take((size_t)4096 * 1024 * 4);           // 16 MB
    __hip_bfloat16* xn    = (__hip_bfloat16*)take((size_t)4096 * 1024 * 2);  // 8 MB
    __hip_bfloat16* qkb   = (__hip_bfloat16*)take((size_t)4096 * 2048 * 2);  // 16 MB
    __hip_bfloat16* Vt    = (__hip_bfloat16*)take((size_t)2048 * 2048 * 2);  // 8 MB
    __hip_bfloat16* attn  = (__hip_bfloat16*)take((size_t)4096 * 1024 * 2);  // 8 MB
    __hip_bfloat16* ffn1  = qkb;  // FFN1 out (32 MB) reuses qkb+Vt+attn

    transpose_to_bf16<<<dim3(3072 / 32, 1024 / 32), 256, 0, stream>>>(qkv_w, wqkv, 1024, 3072);
    transpose_to_bf16<<<dim3(1024 / 32, 1024 / 32), 256, 0, stream>>>(proj_w, wproj, 1024, 1024);
    transpose_to_bf16<<<dim3(4096 / 32, 1024 / 32), 256, 0, stream>>>(ffn_w1, wff1, 1024, 4096);
    transpose_to_bf16<<<dim3(1024 / 32, 4096 / 32), 256, 0, stream>>>(ffn_w2, wff2, 4096, 1024);

    // LN1
    ln_kernel<<<4096, 256, 0, stream>>>(x, ln1_w, ln1_b, xn);
    // QKV with q|k / V^T scatter
    gemm_kernel<3><<<dim3(24, 32), 256, 0, stream>>>(
        xn, wqkv, qkv_b, nullptr, qkb, Vt, 4096, 3072, 1024);
    // Attention
    attn_kernel<<<1024, 256, 0, stream>>>(qkb, Vt, attn);
    // proj + residual(x) -> h (fp32)
    gemm_kernel<0><<<dim3(8, 32), 256, 0, stream>>>(
        attn, wproj, proj_b, x, hbuf, nullptr, 4096, 1024, 1024);
    // LN2 -> y
    ln_kernel<<<4096, 256, 0, stream>>>(hbuf, ln2_w, ln2_b, xn);
    // FFN1 + exact GELU
    gemm_kernel<2><<<dim3(32, 32), 256, 0, stream>>>(
        xn, wff1, ffn_b1, nullptr, ffn1, nullptr, 4096, 4096, 1024);
    // FFN2 + residual(h) -> out (fp32)
    gemm_kernel<0><<<dim3(8, 32), 256, 0, stream>>>(
        ffn1, wff2, ffn_b2, hbuf, outp, nullptr, 4096, 1024, 4096);
}

// Round 4
// 273.472 us; speedup vs baseline: 1.8155x; 1.1545x over previous
//
#include <hip/hip_runtime.h>
#include <hip/hip_bf16.h>
#include <math.h>

typedef __attribute__((ext_vector_type(8))) short bf16x8;
typedef __attribute__((ext_vector_type(4))) float f32x4;
typedef __attribute__((ext_vector_type(4))) unsigned u32x4;

#define MFMA16(a, b, c) __builtin_amdgcn_mfma_f32_16x16x32_bf16((a), (b), (c), 0, 0, 0)

typedef const __attribute__((address_space(1))) void* gas_ptr;
typedef __attribute__((address_space(3))) void* las_ptr;

__device__ __forceinline__ unsigned pack_bf16(float a, float b) {
    unsigned ua = (unsigned)__bfloat16_as_ushort(__float2bfloat16(a));
    unsigned ub = (unsigned)__bfloat16_as_ushort(__float2bfloat16(b));
    return ua | (ub << 16);
}

// ---------------------------------------------------------------------------
// Transpose + fp32 -> bf16 convert:  in[K][N] f32  ->  out[N][K] bf16
// ---------------------------------------------------------------------------
__global__ __launch_bounds__(256)
void transpose_to_bf16(const float* __restrict__ in, __hip_bfloat16* __restrict__ out,
                       int K, int N)
{
    __shared__ float t[32][33];
    const int tx = threadIdx.x & 31, ty = threadIdx.x >> 5;
    const int n0 = blockIdx.x * 32, k0 = blockIdx.y * 32;
    #pragma unroll
    for (int j = 0; j < 32; j += 8)
        t[ty + j][tx] = in[(size_t)(k0 + ty + j) * N + n0 + tx];
    __syncthreads();
    #pragma unroll
    for (int j = 0; j < 32; j += 8)
        out[(size_t)(n0 + ty + j) * K + k0 + tx] = __float2bfloat16(t[tx][ty + j]);
}

// ---------------------------------------------------------------------------
// LayerNorm over D=1024, one block per row, fp32 in -> bf16 out
// ---------------------------------------------------------------------------
__global__ __launch_bounds__(256)
void ln_kernel(const float* __restrict__ in, const float* __restrict__ w,
               const float* __restrict__ b, __hip_bfloat16* __restrict__ out)
{
    const int row = blockIdx.x;
    const int tid = threadIdx.x;
    const float4 v = reinterpret_cast<const float4*>(in + (size_t)row * 1024)[tid];
    float s  = v.x + v.y + v.z + v.w;
    float s2 = v.x * v.x + v.y * v.y + v.z * v.z + v.w * v.w;
    #pragma unroll
    for (int off = 32; off > 0; off >>= 1) {
        s  += __shfl_down(s,  off);
        s2 += __shfl_down(s2, off);
    }
    __shared__ float red[8];
    const int wv = tid >> 6, ln = tid & 63;
    if (ln == 0) { red[wv] = s; red[4 + wv] = s2; }
    __syncthreads();
    s  = red[0] + red[1] + red[2] + red[3];
    s2 = red[4] + red[5] + red[6] + red[7];
    const float mu   = s * (1.0f / 1024.0f);
    const float var  = s2 * (1.0f / 1024.0f) - mu * mu;
    const float rstd = rsqrtf(var + 1e-5f);
    const float4 wv4 = reinterpret_cast<const float4*>(w)[tid];
    const float4 bv4 = reinterpret_cast<const float4*>(b)[tid];
    const size_t o = (size_t)row * 1024 + tid * 4;
    out[o + 0] = __float2bfloat16((v.x - mu) * rstd * wv4.x + bv4.x);
    out[o + 1] = __float2bfloat16((v.y - mu) * rstd * wv4.y + bv4.y);
    out[o + 2] = __float2bfloat16((v.z - mu) * rstd * wv4.z + bv4.z);
    out[o + 3] = __float2bfloat16((v.w - mu) * rstd * wv4.w + bv4.w);
}

// ---------------------------------------------------------------------------
// OLD GEMM (m97 structure), kept for proj: C = A * Bt^T + bias + resid (f32).
// ---------------------------------------------------------------------------
__global__ __launch_bounds__(256)
void gemm_kernel(const __hip_bfloat16* __restrict__ A,
                 const __hip_bfloat16* __restrict__ Bt,
                 const float* __restrict__ bias,
                 const float* __restrict__ resid,
                 float* __restrict__ C0,
                 int M, int N, int K)
{
    __shared__ __align__(16) __hip_bfloat16 Alds[128 * 32];
    __shared__ __align__(16) __hip_bfloat16 Blds[128 * 32];
    const int tid  = threadIdx.x;
    const int lane = tid & 63;
    const int w    = tid >> 6;
    const int wr   = w >> 1, wc = w & 1;
    const int fr   = lane & 15, fq = lane >> 4;

    const int nwg = gridDim.x * gridDim.y;
    int flat = blockIdx.y * gridDim.x + blockIdx.x;
    flat = (flat & 7) * (nwg >> 3) + (flat >> 3);
    const int bx = flat % gridDim.x, by = flat / gridDim.x;
    const int m0 = by * 128, n0 = bx * 128;

    const int srow = lane >> 2;
    const int scol = (lane & 3) * 8;
    const __hip_bfloat16* Ag = A  + (size_t)(m0 + w * 32 + srow) * K + scol;
    const __hip_bfloat16* Bg = Bt + (size_t)(n0 + w * 32 + srow) * K + scol;
    __hip_bfloat16* Al = &Alds[(w * 32) * 32];
    __hip_bfloat16* Bl = &Blds[(w * 32) * 32];

    f32x4 acc[4][4] = {};

    for (int k0 = 0; k0 < K; k0 += 32) {
        __syncthreads();
        __builtin_amdgcn_global_load_lds((gas_ptr)(const void*)(Ag + k0),
                                         (las_ptr)(void*)Al, 16, 0, 0);
        __builtin_amdgcn_global_load_lds((gas_ptr)(const void*)(Ag + (size_t)16 * K + k0),
                                         (las_ptr)(void*)(Al + 16 * 32), 16, 0, 0);
        __builtin_amdgcn_global_load_lds((gas_ptr)(const void*)(Bg + k0),
                                         (las_ptr)(void*)Bl, 16, 0, 0);
        __builtin_amdgcn_global_load_lds((gas_ptr)(const void*)(Bg + (size_t)16 * K + k0),
                                         (las_ptr)(void*)(Bl + 16 * 32), 16, 0, 0);
        __syncthreads();
        bf16x8 af[4], bg[4];
        #pragma unroll
        for (int m = 0; m < 4; ++m)
            af[m] = *reinterpret_cast<const bf16x8*>(&Alds[(wr * 64 + m * 16 + fr) * 32 + fq * 8]);
        #pragma unroll
        for (int n = 0; n < 4; ++n)
            bg[n] = *reinterpret_cast<const bf16x8*>(&Blds[(wc * 64 + n * 16 + fr) * 32 + fq * 8]);
        #pragma unroll
        for (int m = 0; m < 4; ++m)
            #pragma unroll
            for (int n = 0; n < 4; ++n)
                acc[m][n] = MFMA16(af[m], bg[n], acc[m][n]);
    }

    #pragma unroll
    for (int n = 0; n < 4; ++n) {
        const int col = n0 + wc * 64 + n * 16 + fr;
        const float bv = bias[col];
        #pragma unroll
        for (int m = 0; m < 4; ++m) {
            #pragma unroll
            for (int i = 0; i < 4; ++i) {
                const int row = m0 + wr * 64 + m * 16 + fq * 4 + i;
                float v = acc[m][n][i] + bv + resid[(size_t)row * N + col];
                C0[(size_t)row * N + col] = v;
            }
        }
    }
}

// ---------------------------------------------------------------------------
// NEW pipelined GEMM: 256 x BN tile, BK=32, 8 waves (512 thr), 4-slot LDS ring,
// counted vmcnt (T4), raw s_barrier (1/iter), XOR-swizzled LDS (T2),
// setprio MFMA cluster (T5), XCD swizzle (T1).
// Logical LDS tile (r, k): phys row r>>1 (64 el), el = (32*(r&1)+k)^(8*((r>>1)&7)).
// MODE 2: bf16 out + exact GELU + bias
// MODE 3: QKV: cols<2048 -> C0[row*2048+col] bf16; else V^T scatter to C1
// MODE 4: f32 partial (no bias): z0 -> P0, z1 -> P1  (split-K)
// ---------------------------------------------------------------------------
template<int BN, int MODE>
__global__ __launch_bounds__(512)
void gemm256(const __hip_bfloat16* __restrict__ A,
             const __hip_bfloat16* __restrict__ Bt,
             const float* __restrict__ bias,
             void* __restrict__ C0, void* __restrict__ C1,
             int N, int K, int KS)
{
    constexpr int WN  = BN / 64;       // waves along N
    constexpr int WM  = 8 / WN;        // waves along M
    constexpr int MR  = 256 / WM / 16; // A frags / wave
    constexpr int NLB = BN / 128;      // B gloads / thread / K-tile
    constexpr int LPI = 2 + NLB;       // gloads / thread / K-tile
    constexpr int ASZ = 8192;          // A slot elements (256x32)
    constexpr int BSZ = BN * 32;       // B slot elements
    constexpr int SLOT = ASZ + BSZ;

    __shared__ __align__(16) __hip_bfloat16 lds[4 * SLOT];

    const int tid  = threadIdx.x;
    const int lane = tid & 63;
    const int w    = tid >> 6;
    const int wr   = w / WN, wcn = w % WN;
    const int fr   = lane & 15, fq = lane >> 4;
    const int wmbase = wr * (MR * 16);
    const int wnbase = wcn * 64;

    // XCD swizzle over x*y (all grids %8==0)
    const int nwg = gridDim.x * gridDim.y;
    int flat = blockIdx.y * gridDim.x + blockIdx.x;
    flat = (flat & 7) * (nwg >> 3) + (flat >> 3);
    const int bx = flat % gridDim.x, by = flat / gridDim.x;
    const int m0 = by * 256, n0 = bx * BN;
    const int kbase = blockIdx.z * KS;
    const int NT = KS >> 5;

    // ---- staging lane geometry: phys row pr, 16B chunk ch ----
    const int prc = w * 8 + (lane >> 3);
    const int ch  = lane & 7;
    // logical (row, kcol) for phys (pr, ch):
    auto srcRow = [&](int pr) { int v = ch ^ (pr & 7); return 2 * pr + (v >> 2); };
    auto srcCol = [&](int pr) { int v = ch ^ (pr & 7); return 8 * (v & 3); };

    const __hip_bfloat16* aS[2];
    const __hip_bfloat16* bS[2];
    #pragma unroll
    for (int j = 0; j < 2; ++j) {
        const int pr = prc + 64 * j;
        aS[j] = A + (size_t)(m0 + srcRow(pr)) * K + kbase + srcCol(pr);
    }
    #pragma unroll
    for (int j = 0; j < NLB; ++j) {
        const int pr = prc + 64 * j;
        bS[j] = Bt + (size_t)(n0 + srcRow(pr)) * K + kbase + srcCol(pr);
    }

    auto stage = [&](int kt) {
        const int s = kt & 3;
        __hip_bfloat16* LA = &lds[s * SLOT];
        __hip_bfloat16* LB = LA + ASZ;
        #pragma unroll
        for (int j = 0; j < 2; ++j)
            __builtin_amdgcn_global_load_lds((gas_ptr)(const void*)(aS[j] + kt * 32),
                                             (las_ptr)(void*)(LA + w * 512 + j * 4096), 16, 0, 0);
        #pragma unroll
        for (int j = 0; j < NLB; ++j)
            __builtin_amdgcn_global_load_lds((gas_ptr)(const void*)(bS[j] + kt * 32),
                                             (las_ptr)(void*)(LB + w * 512 + j * 4096), 16, 0, 0);
    };

    f32x4 acc[MR][4] = {};

    stage(0); stage(1); stage(2);

    for (int kt = 0; kt < NT; ++kt) {
        if (kt + 2 < NT)
            asm volatile("s_waitcnt vmcnt(%0)" :: "i"(2 * LPI) : "memory");
        else if (kt + 1 < NT)
            asm volatile("s_waitcnt vmcnt(%0)" :: "i"(LPI) : "memory");
        else
            asm volatile("s_waitcnt vmcnt(0)" ::: "memory");
        __builtin_amdgcn_s_barrier();
        __builtin_amdgcn_sched_barrier(0);

        if (kt + 3 < NT) stage(kt + 3);

        const __hip_bfloat16* LA = &lds[(kt & 3) * SLOT];
        const __hip_bfloat16* LB = LA + ASZ;
        bf16x8 af[MR], bg[4];
        #pragma unroll
        for (int m = 0; m < MR; ++m) {
            const int r = wmbase + m * 16 + fr;
            af[m] = *reinterpret_cast<const bf16x8*>(
                &LA[(r >> 1) * 64 + (((r & 1) * 32 + fq * 8) ^ (((r >> 1) & 7) * 8))]);
        }
        #pragma unroll
        for (int n = 0; n < 4; ++n) {
            const int r = wnbase + n * 16 + fr;
            bg[n] = *reinterpret_cast<const bf16x8*>(
                &LB[(r >> 1) * 64 + (((r & 1) * 32 + fq * 8) ^ (((r >> 1) & 7) * 8))]);
        }

        __builtin_amdgcn_s_setprio(1);
        #pragma unroll
        for (int m = 0; m < MR; ++m)
            #pragma unroll
            for (int n = 0; n < 4; ++n)
                acc[m][n] = MFMA16(af[m], bg[n], acc[m][n]);
        __builtin_amdgcn_s_setprio(0);
    }

    // ---- epilogue ----
    #pragma unroll
    for (int n = 0; n < 4; ++n) {
        const int col = n0 + wnbase + n * 16 + fr;
        float bv = 0.0f;
        if (MODE != 4) bv = bias[col];
        #pragma unroll
        for (int m = 0; m < MR; ++m) {
            #pragma unroll
            for (int i = 0; i < 4; ++i) {
                const int row = m0 + wmbase + m * 16 + fq * 4 + i;
                float v = acc[m][n][i] + bv;
                if (MODE == 2) {
                    v = 0.5f * v * (1.0f + erff(v * 0.70710678118654752f));
                    reinterpret_cast<__hip_bfloat16*>(C0)[(size_t)row * N + col] =
                        __float2bfloat16(v);
                } else if (MODE == 3) {
                    if (col < 2048) {
                        reinterpret_cast<__hip_bfloat16*>(C0)[((size_t)row << 11) + col] =
                            __float2bfloat16(v);
                    } else {
                        const int b = row >> 11, l = row & 2047;
                        const int hc = col - 2048;
                        reinterpret_cast<__hip_bfloat16*>(C1)[((size_t)(b * 1024 + hc) << 11) + l] =
                            __float2bfloat16(v);
                    }
                } else {  // MODE 4: f32 partial
                    float* dst = blockIdx.z ? reinterpret_cast<float*>(C1)
                                            : reinterpret_cast<float*>(C0);
                    dst[(size_t)row * N + col] = v;
                }
            }
        }
    }
}

// ---------------------------------------------------------------------------
// FFN2 finish: out = p0 + out(partial1) + h + bias   (all f32, float4 lanes)
// ---------------------------------------------------------------------------
__global__ __launch_bounds__(256)
void ffn2_reduce(const float4* __restrict__ p0, float4* __restrict__ outv,
                 const float4* __restrict__ h, const float4* __restrict__ bias)
{
    const int i = blockIdx.x * 256 + threadIdx.x;
    const float4 a = p0[i], b = outv[i], c = h[i], d = bias[i & 255];
    float4 r;
    r.x = a.x + b.x + c.x + d.x;
    r.y = a.y + b.y + c.y + d.y;
    r.z = a.z + b.z + c.z + d.z;
    r.w = a.w + b.w + c.w + d.w;
    outv[i] = r;
}

// ---------------------------------------------------------------------------
// Causal flash attention (round-3 version, unchanged).
// ---------------------------------------------------------------------------
__global__ __launch_bounds__(256)
void attn_kernel(const __hip_bfloat16* __restrict__ qk,
                 const __hip_bfloat16* __restrict__ Vt,
                 __hip_bfloat16* __restrict__ out)
{
    const int bid  = blockIdx.x;
    const int xcd  = bid & 7;
    const int rank = bid >> 3;
    const int panel = xcd * 4 + (rank & 3);
    const int qt   = 31 - (rank >> 2);
    const int h = panel & 15, b = panel >> 4;
    const int q0 = qt * 64;

    const int lane = threadIdx.x & 63;
    const int w    = threadIdx.x >> 6;
    const int fr   = lane & 15, fq = lane >> 4;
    const int qrow = q0 + w * 16 + fr;

    __shared__ __align__(16) __hip_bfloat16 Klds[2][64 * 64];
    __shared__ __align__(16) __hip_bfloat16 Vlds[2][64 * 64];

    bf16x8 qf[2];
    {
        const __hip_bfloat16* qp = qk + ((size_t)(b * 2048 + qrow) << 11) + h * 64 + fq * 8;
        qf[0] = *reinterpret_cast<const bf16x8*>(qp);
        qf[1] = *reinterpret_cast<const bf16x8*>(qp + 32);
    }

    const int srow8 = lane >> 3;
    const int sc    = lane & 7;
    const __hip_bfloat16* Kg[2];
    const __hip_bfloat16* Vg[2];
    #pragma unroll
    for (int j = 0; j < 2; ++j) {
        const int r = w * 16 + j * 8 + srow8;
        const int csw = (sc ^ (r & 7)) * 8;
        Kg[j] = qk + ((size_t)(b * 2048 + r) << 11) + 1024 + h * 64 + csw;
        Vg[j] = Vt + ((size_t)(b * 1024 + h * 64 + r) << 11) + csw;
    }

    auto stage = [&](int kv0, int bufi) {
        __hip_bfloat16* KL = &Klds[bufi][0];
        __hip_bfloat16* VL = &Vlds[bufi][0];
        #pragma unroll
        for (int j = 0; j < 2; ++j) {
            __builtin_amdgcn_global_load_lds(
                (gas_ptr)(const void*)(Kg[j] + ((size_t)kv0 << 11)),
                (las_ptr)(void*)&KL[(w * 16 + j * 8) * 64], 16, 0, 0);
            __builtin_amdgcn_global_load_lds(
                (gas_ptr)(const void*)(Vg[j] + kv0),
                (las_ptr)(void*)&VL[(w * 16 + j * 8) * 64], 16, 0, 0);
        }
    };

    const float SC = 0.125f * 1.44269504088896f;
    float m_run = -1e30f, l_run = 0.0f;
    f32x4 o[4] = {};

    const int ntiles = qt + 1;
    stage(0, 0);
    int cur = 0;

    for (int t = 0; t < ntiles; ++t) {
        const int kv0 = t << 6;
        __syncthreads();
        if (t + 1 < ntiles) stage((t + 1) << 6, cur ^ 1);

        const __hip_bfloat16* Kl = &Klds[cur][0];
        const __hip_bfloat16* Vl = &Vlds[cur][0];

        f32x4 s[4] = {};
        #pragma unroll
        for (int n = 0; n < 4; ++n) {
            const int row = n * 16 + fr;
            const int sw = (row & 7) << 3;
            const bf16x8 k0 = *reinterpret_cast<const bf16x8*>(&Kl[row * 64 + ((fq * 8) ^ sw)]);
            const bf16x8 k1 = *reinterpret_cast<const bf16x8*>(&Kl[row * 64 + ((fq * 8 + 32) ^ sw)]);
            s[n] = MFMA16(k0, qf[0], s[n]);
            s[n] = MFMA16(k1, qf[1], s[n]);
        }

        float pm = -1e30f;
        if (t == ntiles - 1) {
            #pragma unroll
            for (int n = 0; n < 4; ++n)
                #pragma unroll
                for (int i = 0; i < 4; ++i) {
                    const int kvp = kv0 + n * 16 + fq * 4 + i;
                    float sv = s[n][i] * SC;
                    sv = (kvp <= qrow) ? sv : -1e30f;
                    s[n][i] = sv;
                    pm = fmaxf(pm, sv);
                }
        } else {
            #pragma unroll
            for (int n = 0; n < 4; ++n)
                #pragma unroll
                for (int i = 0; i < 4; ++i) {
                    const float sv = s[n][i] * SC;
                    s[n][i] = sv;
                    pm = fmaxf(pm, sv);
                }
        }
        pm = fmaxf(pm, __shfl_xor(pm, 16));
        pm = fmaxf(pm, __shfl_xor(pm, 32));
        const float mnew = fmaxf(m_run, pm);
        const float corr = exp2f(m_run - mnew);
        m_run = mnew;

        float rs = 0.0f;
        unsigned pk[8];
        #pragma unroll
        for (int n = 0; n < 4; ++n) {
            const float p0 = exp2f(s[n][0] - mnew);
            const float p1 = exp2f(s[n][1] - mnew);
            const float p2 = exp2f(s[n][2] - mnew);
            const float p3 = exp2f(s[n][3] - mnew);
            rs += (p0 + p1) + (p2 + p3);
            pk[n * 2 + 0] = pack_bf16(p0, p1);
            pk[n * 2 + 1] = pack_bf16(p2, p3);
        }
        rs += __shfl_xor(rs, 16);
        rs += __shfl_xor(rs, 32);
        l_run = l_run * corr + rs;

        #pragma unroll
        for (int i = 0; i < 4; ++i) {
            const float ci = __shfl(corr, fq * 4 + i);
            o[0][i] *= ci; o[1][i] *= ci; o[2][i] *= ci; o[3][i] *= ci;
        }

        u32x4 A0, A1;
        #pragma unroll
        for (int r = 0; r < 4; ++r) {
            const int sl = fr + ((2 * (fq & 1) + (r >> 1)) << 4);
            const unsigned lo0 = __shfl(pk[0 + (r & 1)], sl);
            const unsigned hi0 = __shfl(pk[2 + (r & 1)], sl);
            const unsigned lo1 = __shfl(pk[4 + (r & 1)], sl);
            const unsigned hi1 = __shfl(pk[6 + (r & 1)], sl);
            A0[r] = (fq & 2) ? hi0 : lo0;
            A1[r] = (fq & 2) ? hi1 : lo1;
        }
        const bf16x8 pa0 = __builtin_bit_cast(bf16x8, A0);
        const bf16x8 pa1 = __builtin_bit_cast(bf16x8, A1);

        #pragma unroll
        for (int tt = 0; tt < 4; ++tt) {
            const int row = tt * 16 + fr;
            const int sw = (row & 7) << 3;
            const bf16x8 v0 = *reinterpret_cast<const bf16x8*>(&Vl[row * 64 + ((fq * 8) ^ sw)]);
            const bf16x8 v1 = *reinterpret_cast<const bf16x8*>(&Vl[row * 64 + ((fq * 8 + 32) ^ sw)]);
            o[tt] = MFMA16(pa0, v0, o[tt]);
            o[tt] = MFMA16(pa1, v1, o[tt]);
        }
        cur ^= 1;
    }

    #pragma unroll
    for (int i = 0; i < 4; ++i) {
        const float li  = __shfl(l_run, fq * 4 + i);
        const float inv = 1.0f / li;
        const int row = q0 + w * 16 + fq * 4 + i;
        #pragma unroll
        for (int tt = 0; tt < 4; ++tt)
            out[(size_t)(b * 2048 + row) * 1024 + h * 64 + tt * 16 + fr] =
                __float2bfloat16(o[tt][i] * inv);
    }
}

// ---------------------------------------------------------------------------
extern "C" void kernel_launch(void* const* d_in, const int* in_sizes, int n_in,
                              void* d_out, int out_size, void* d_ws, size_t ws_size,
                              hipStream_t stream)
{
    (void)in_sizes; (void)n_in; (void)out_size; (void)ws_size;
    const float* x      = (const float*)d_in[0];
    const float* ln1_w  = (const float*)d_in[2];
    const float* ln1_b  = (const float*)d_in[3];
    const float* qkv_w  = (const float*)d_in[4];
    const float* qkv_b  = (const float*)d_in[5];
    const float* proj_w = (const float*)d_in[6];
    const float* proj_b = (const float*)d_in[7];
    const float* ln2_w  = (const float*)d_in[8];
    const float* ln2_b  = (const float*)d_in[9];
    const float* ffn_w1 = (const float*)d_in[10];
    const float* ffn_b1 = (const float*)d_in[11];
    const float* ffn_w2 = (const float*)d_in[12];
    const float* ffn_b2 = (const float*)d_in[13];
    float* outp = (float*)d_out;

    char* ws = (char*)d_ws;
    size_t off = 0;
    auto take = [&](size_t bytes) -> char* {
        char* p = ws + off;
        off += (bytes + 255) & ~(size_t)255;
        return p;
    };
    __hip_bfloat16* wqkv  = (__hip_bfloat16*)take((size_t)3072 * 1024 * 2);  // @0,     6 MB
    __hip_bfloat16* wproj = (__hip_bfloat16*)take((size_t)1024 * 1024 * 2);  // @6M,    2 MB
    __hip_bfloat16* wff1  = (__hip_bfloat16*)take((size_t)4096 * 1024 * 2);  // @8M,    8 MB
    __hip_bfloat16* wff2  = (__hip_bfloat16*)take((size_t)1024 * 4096 * 2);  // @16M,   8 MB
    float*          hbuf  = (float*)take((size_t)4096 * 1024 * 4);           // 16 MB
    __hip_bfloat16* xn    = (__hip_bfloat16*)take((size_t)4096 * 1024 * 2);  // 8 MB
    __hip_bfloat16* qkb   = (__hip_bfloat16*)take((size_t)4096 * 2048 * 2);  // 16 MB
    __hip_bfloat16* Vt    = (__hip_bfloat16*)take((size_t)2048 * 2048 * 2);  // 8 MB
    __hip_bfloat16* attn  = (__hip_bfloat16*)take((size_t)4096 * 1024 * 2);  // 8 MB
    __hip_bfloat16* ffn1  = qkb;  // FFN1 out (32 MB) reuses qkb+Vt+attn
    // FFN2 split-K partials: p0 overlays wqkv+wproj+wff1 (exactly 16 MB, dead
    // by FFN2); p1 = d_out (rewritten in-place by ffn2_reduce).
    float* part0 = (float*)ws;

    transpose_to_bf16<<<dim3(3072 / 32, 1024 / 32), 256, 0, stream>>>(qkv_w, wqkv, 1024, 3072);
    transpose_to_bf16<<<dim3(1024 / 32, 1024 / 32), 256, 0, stream>>>(proj_w, wproj, 1024, 1024);
    transpose_to_bf16<<<dim3(4096 / 32, 1024 / 32), 256, 0, stream>>>(ffn_w1, wff1, 1024, 4096);
    transpose_to_bf16<<<dim3(1024 / 32, 4096 / 32), 256, 0, stream>>>(ffn_w2, wff2, 4096, 1024);

    // LN1
    ln_kernel<<<4096, 256, 0, stream>>>(x, ln1_w, ln1_b, xn);
    // QKV (q|k -> qkb, V^T -> Vt)
    gemm256<256, 3><<<dim3(12, 16, 1), 512, 0, stream>>>(
        xn, wqkv, qkv_b, qkb, Vt, 3072, 1024, 1024);
    // Attention
    attn_kernel<<<1024, 256, 0, stream>>>(qkb, Vt, attn);
    // proj + residual(x) -> h (fp32)  [old kernel]
    gemm_kernel<<<dim3(8, 32), 256, 0, stream>>>(
        attn, wproj, proj_b, x, hbuf, 4096, 1024, 1024);
    // LN2 -> y
    ln_kernel<<<4096, 256, 0, stream>>>(hbuf, ln2_w, ln2_b, xn);
    // FFN1 + exact GELU
    gemm256<256, 2><<<dim3(16, 16, 1), 512, 0, stream>>>(
        xn, wff1, ffn_b1, ffn1, nullptr, 4096, 1024, 1024);
    // FFN2 split-K=2: z=0 -> part0, z=1 -> d_out
    gemm256<128, 4><<<dim3(8, 16, 2), 512, 0, stream>>>(
        ffn1, wff2, nullptr, part0, outp, 1024, 4096, 2048);
    // out = part0 + out + h + bias
    ffn2_reduce<<<4096, 256, 0, stream>>>(
        (const float4*)part0, (float4*)outp, (const float4*)hbuf, (const float4*)ffn_b2);
}

// Round 5
// 242.936 us; speedup vs baseline: 2.0437x; 1.1257x over previous
//
#include <hip/hip_runtime.h>
#include <hip/hip_bf16.h>
#include <math.h>

typedef __attribute__((ext_vector_type(8))) short bf16x8;
typedef __attribute__((ext_vector_type(4))) float f32x4;
typedef __attribute__((ext_vector_type(4))) unsigned u32x4;

#define MFMA16(a, b, c) __builtin_amdgcn_mfma_f32_16x16x32_bf16((a), (b), (c), 0, 0, 0)

typedef const __attribute__((address_space(1))) void* gas_ptr;
typedef __attribute__((address_space(3))) void* las_ptr;

__device__ __forceinline__ unsigned pack_bf16(float a, float b) {
    unsigned ua = (unsigned)__bfloat16_as_ushort(__float2bfloat16(a));
    unsigned ub = (unsigned)__bfloat16_as_ushort(__float2bfloat16(b));
    return ua | (ub << 16);
}

// ---------------------------------------------------------------------------
// Transpose + fp32 -> bf16 convert:  in[K][N] f32  ->  out[N][K] bf16
// ---------------------------------------------------------------------------
__global__ __launch_bounds__(256)
void transpose_to_bf16(const float* __restrict__ in, __hip_bfloat16* __restrict__ out,
                       int K, int N)
{
    __shared__ float t[32][33];
    const int tx = threadIdx.x & 31, ty = threadIdx.x >> 5;
    const int n0 = blockIdx.x * 32, k0 = blockIdx.y * 32;
    #pragma unroll
    for (int j = 0; j < 32; j += 8)
        t[ty + j][tx] = in[(size_t)(k0 + ty + j) * N + n0 + tx];
    __syncthreads();
    #pragma unroll
    for (int j = 0; j < 32; j += 8)
        out[(size_t)(n0 + ty + j) * K + k0 + tx] = __float2bfloat16(t[tx][ty + j]);
}

// ---------------------------------------------------------------------------
// LayerNorm over D=1024, one block per row, fp32 in -> bf16 out
// ---------------------------------------------------------------------------
__global__ __launch_bounds__(256)
void ln_kernel(const float* __restrict__ in, const float* __restrict__ w,
               const float* __restrict__ b, __hip_bfloat16* __restrict__ out)
{
    const int row = blockIdx.x;
    const int tid = threadIdx.x;
    const float4 v = reinterpret_cast<const float4*>(in + (size_t)row * 1024)[tid];
    float s  = v.x + v.y + v.z + v.w;
    float s2 = v.x * v.x + v.y * v.y + v.z * v.z + v.w * v.w;
    #pragma unroll
    for (int off = 32; off > 0; off >>= 1) {
        s  += __shfl_down(s,  off);
        s2 += __shfl_down(s2, off);
    }
    __shared__ float red[8];
    const int wv = tid >> 6, ln = tid & 63;
    if (ln == 0) { red[wv] = s; red[4 + wv] = s2; }
    __syncthreads();
    s  = red[0] + red[1] + red[2] + red[3];
    s2 = red[4] + red[5] + red[6] + red[7];
    const float mu   = s * (1.0f / 1024.0f);
    const float var  = s2 * (1.0f / 1024.0f) - mu * mu;
    const float rstd = rsqrtf(var + 1e-5f);
    const float4 wv4 = reinterpret_cast<const float4*>(w)[tid];
    const float4 bv4 = reinterpret_cast<const float4*>(b)[tid];
    const size_t o = (size_t)row * 1024 + tid * 4;
    out[o + 0] = __float2bfloat16((v.x - mu) * rstd * wv4.x + bv4.x);
    out[o + 1] = __float2bfloat16((v.y - mu) * rstd * wv4.y + bv4.y);
    out[o + 2] = __float2bfloat16((v.z - mu) * rstd * wv4.z + bv4.z);
    out[o + 3] = __float2bfloat16((v.w - mu) * rstd * wv4.w + bv4.w);
}

// ---------------------------------------------------------------------------
// Pipelined GEMM: 128x128 tile, BK=32, 4 waves (256 thr), 3-slot LDS ring
// (48 KiB -> 3 blocks/CU), counted vmcnt, raw s_barrier, XOR-swizzled LDS
// (pre-swizzled global source + swizzled ds_read), setprio MFMA cluster,
// XCD 4x4-square swizzle (2 MB working set per XCD -> L2-fit).
// Logical LDS tile (r,k): phys row r>>1 (64 el), el = (32*(r&1)+k)^(8*((r>>1)&7)).
// MODE 0: f32 out = acc + bias + resid(f32)
// MODE 2: bf16 out + exact GELU + bias
// MODE 3: QKV: tile entirely q|k (n0<2048) -> C0[row*2048+col] bf16;
//         else V^T packed scatter to C1[(b*1024+hc)*2048 + l] (8B stores)
// ---------------------------------------------------------------------------
template<int MODE>
__global__ __launch_bounds__(256, 3)
void gemm128p(const __hip_bfloat16* __restrict__ A,
              const __hip_bfloat16* __restrict__ Bt,
              const float* __restrict__ bias,
              const float* __restrict__ resid,
              void* __restrict__ C0, void* __restrict__ C1,
              int N, int K)
{
    constexpr int SLOT = 8192;  // elements: A 4096 + B 4096 (16 KiB)
    __shared__ __align__(16) __hip_bfloat16 lds[3 * SLOT];

    const int tid  = threadIdx.x;
    const int lane = tid & 63;
    const int w    = tid >> 6;
    const int wr   = w >> 1, wc = w & 1;
    const int fr   = lane & 15, fq = lane >> 4;

    // ---- XCD 4x4-square swizzle (needs gx%4==0, gy%4==0, (gx*gy/16)%8==0) ----
    const int gx  = gridDim.x;
    const int nsq = (gx * gridDim.y) >> 4;
    const int ngx = gx >> 2;
    const int flat = blockIdx.y * gx + blockIdx.x;
    const int idx  = flat >> 3;
    const int sq   = (flat & 7) * (nsq >> 3) + (idx >> 4);
    const int pos  = idx & 15;
    const int bx = (sq % ngx) * 4 + (pos & 3);
    const int by = (sq / ngx) * 4 + (pos >> 2);
    const int m0 = by * 128, n0 = bx * 128;
    const int NT = K >> 5;

    // ---- staging geometry: phys row pr, 16B chunk ch ----
    const int prc = w * 8 + (lane >> 3);   // 0..31 (j adds 32)
    const int ch  = lane & 7;
    const __hip_bfloat16* aS[2];
    const __hip_bfloat16* bS[2];
    #pragma unroll
    for (int j = 0; j < 2; ++j) {
        const int pr  = prc + 32 * j;
        const int v   = ch ^ (pr & 7);
        const int row = 2 * pr + (v >> 2);
        const int col = 8 * (v & 3);
        aS[j] = A  + (size_t)(m0 + row) * K + col;
        bS[j] = Bt + (size_t)(n0 + row) * K + col;
    }

    auto stage = [&](int kt, int s) {
        __hip_bfloat16* LA = &lds[s * SLOT];
        __hip_bfloat16* LB = LA + 4096;
        #pragma unroll
        for (int j = 0; j < 2; ++j) {
            __builtin_amdgcn_global_load_lds((gas_ptr)(const void*)(aS[j] + kt * 32),
                                             (las_ptr)(void*)(LA + w * 512 + j * 2048), 16, 0, 0);
            __builtin_amdgcn_global_load_lds((gas_ptr)(const void*)(bS[j] + kt * 32),
                                             (las_ptr)(void*)(LB + w * 512 + j * 2048), 16, 0, 0);
        }
    };

    f32x4 acc[4][4] = {};

    stage(0, 0);
    stage(1, 1);
    int sl = 0, sp = 2;  // slot of kt, slot of kt+2

    for (int kt = 0; kt < NT; ++kt) {
        // slot kt resident (4 loads of kt+1 may stay in flight); own ds_reads done
        if (kt + 1 < NT)
            asm volatile("s_waitcnt vmcnt(4) lgkmcnt(0)" ::: "memory");
        else
            asm volatile("s_waitcnt vmcnt(0) lgkmcnt(0)" ::: "memory");
        __builtin_amdgcn_s_barrier();
        __builtin_amdgcn_sched_barrier(0);

        if (kt + 2 < NT) stage(kt + 2, sp);

        const __hip_bfloat16* LA = &lds[sl * SLOT];
        const __hip_bfloat16* LB = LA + 4096;
        bf16x8 af[4], bg[4];
        #pragma unroll
        for (int m = 0; m < 4; ++m) {
            const int r = wr * 64 + m * 16 + fr;
            af[m] = *reinterpret_cast<const bf16x8*>(
                &LA[(r >> 1) * 64 + (((r & 1) * 32 + fq * 8) ^ (((r >> 1) & 7) * 8))]);
        }
        #pragma unroll
        for (int n = 0; n < 4; ++n) {
            const int r = wc * 64 + n * 16 + fr;
            bg[n] = *reinterpret_cast<const bf16x8*>(
                &LB[(r >> 1) * 64 + (((r & 1) * 32 + fq * 8) ^ (((r >> 1) & 7) * 8))]);
        }

        __builtin_amdgcn_s_setprio(1);
        #pragma unroll
        for (int m = 0; m < 4; ++m)
            #pragma unroll
            for (int n = 0; n < 4; ++n)
                acc[m][n] = MFMA16(af[m], bg[n], acc[m][n]);
        __builtin_amdgcn_s_setprio(0);

        sl = (sl == 2) ? 0 : sl + 1;
        sp = (sp == 2) ? 0 : sp + 1;
    }

    // ---- epilogue ----
    if (MODE == 3 && n0 >= 2048) {
        // V^T packed scatter: 4 consecutive l per 8B store
        #pragma unroll
        for (int n = 0; n < 4; ++n) {
            const int col = n0 + wc * 64 + n * 16 + fr;
            const int hc  = col - 2048;
            const float bv = bias[col];
            #pragma unroll
            for (int m = 0; m < 4; ++m) {
                const int r0 = m0 + wr * 64 + m * 16 + fq * 4;
                const int b = r0 >> 11, l0 = r0 & 2047;
                const unsigned lo = pack_bf16(acc[m][n][0] + bv, acc[m][n][1] + bv);
                const unsigned hi = pack_bf16(acc[m][n][2] + bv, acc[m][n][3] + bv);
                uint2 pv; pv.x = lo; pv.y = hi;
                *reinterpret_cast<uint2*>(
                    &reinterpret_cast<__hip_bfloat16*>(C1)[((size_t)(b * 1024 + hc) << 11) + l0]) = pv;
            }
        }
        return;
    }

    #pragma unroll
    for (int n = 0; n < 4; ++n) {
        const int col = n0 + wc * 64 + n * 16 + fr;
        const float bv = bias[col];
        #pragma unroll
        for (int m = 0; m < 4; ++m) {
            #pragma unroll
            for (int i = 0; i < 4; ++i) {
                const int row = m0 + wr * 64 + m * 16 + fq * 4 + i;
                float v = acc[m][n][i] + bv;
                if (MODE == 2) {
                    v = 0.5f * v * (1.0f + erff(v * 0.70710678118654752f));
                    reinterpret_cast<__hip_bfloat16*>(C0)[(size_t)row * N + col] =
                        __float2bfloat16(v);
                } else if (MODE == 3) {
                    reinterpret_cast<__hip_bfloat16*>(C0)[((size_t)row << 11) + col] =
                        __float2bfloat16(v);
                } else {  // MODE 0
                    v += resid[(size_t)row * N + col];
                    reinterpret_cast<float*>(C0)[(size_t)row * N + col] = v;
                }
            }
        }
    }
}

// ---------------------------------------------------------------------------
// Causal flash attention (unchanged from round 3).
// ---------------------------------------------------------------------------
__global__ __launch_bounds__(256)
void attn_kernel(const __hip_bfloat16* __restrict__ qk,
                 const __hip_bfloat16* __restrict__ Vt,
                 __hip_bfloat16* __restrict__ out)
{
    const int bid  = blockIdx.x;
    const int xcd  = bid & 7;
    const int rank = bid >> 3;
    const int panel = xcd * 4 + (rank & 3);
    const int qt   = 31 - (rank >> 2);
    const int h = panel & 15, b = panel >> 4;
    const int q0 = qt * 64;

    const int lane = threadIdx.x & 63;
    const int w    = threadIdx.x >> 6;
    const int fr   = lane & 15, fq = lane >> 4;
    const int qrow = q0 + w * 16 + fr;

    __shared__ __align__(16) __hip_bfloat16 Klds[2][64 * 64];
    __shared__ __align__(16) __hip_bfloat16 Vlds[2][64 * 64];

    bf16x8 qf[2];
    {
        const __hip_bfloat16* qp = qk + ((size_t)(b * 2048 + qrow) << 11) + h * 64 + fq * 8;
        qf[0] = *reinterpret_cast<const bf16x8*>(qp);
        qf[1] = *reinterpret_cast<const bf16x8*>(qp + 32);
    }

    const int srow8 = lane >> 3;
    const int sc    = lane & 7;
    const __hip_bfloat16* Kg[2];
    const __hip_bfloat16* Vg[2];
    #pragma unroll
    for (int j = 0; j < 2; ++j) {
        const int r = w * 16 + j * 8 + srow8;
        const int csw = (sc ^ (r & 7)) * 8;
        Kg[j] = qk + ((size_t)(b * 2048 + r) << 11) + 1024 + h * 64 + csw;
        Vg[j] = Vt + ((size_t)(b * 1024 + h * 64 + r) << 11) + csw;
    }

    auto stage = [&](int kv0, int bufi) {
        __hip_bfloat16* KL = &Klds[bufi][0];
        __hip_bfloat16* VL = &Vlds[bufi][0];
        #pragma unroll
        for (int j = 0; j < 2; ++j) {
            __builtin_amdgcn_global_load_lds(
                (gas_ptr)(const void*)(Kg[j] + ((size_t)kv0 << 11)),
                (las_ptr)(void*)&KL[(w * 16 + j * 8) * 64], 16, 0, 0);
            __builtin_amdgcn_global_load_lds(
                (gas_ptr)(const void*)(Vg[j] + kv0),
                (las_ptr)(void*)&VL[(w * 16 + j * 8) * 64], 16, 0, 0);
        }
    };

    const float SC = 0.125f * 1.44269504088896f;
    float m_run = -1e30f, l_run = 0.0f;
    f32x4 o[4] = {};

    const int ntiles = qt + 1;
    stage(0, 0);
    int cur = 0;

    for (int t = 0; t < ntiles; ++t) {
        const int kv0 = t << 6;
        __syncthreads();
        if (t + 1 < ntiles) stage((t + 1) << 6, cur ^ 1);

        const __hip_bfloat16* Kl = &Klds[cur][0];
        const __hip_bfloat16* Vl = &Vlds[cur][0];

        f32x4 s[4] = {};
        #pragma unroll
        for (int n = 0; n < 4; ++n) {
            const int row = n * 16 + fr;
            const int sw = (row & 7) << 3;
            const bf16x8 k0 = *reinterpret_cast<const bf16x8*>(&Kl[row * 64 + ((fq * 8) ^ sw)]);
            const bf16x8 k1 = *reinterpret_cast<const bf16x8*>(&Kl[row * 64 + ((fq * 8 + 32) ^ sw)]);
            s[n] = MFMA16(k0, qf[0], s[n]);
            s[n] = MFMA16(k1, qf[1], s[n]);
        }

        float pm = -1e30f;
        if (t == ntiles - 1) {
            #pragma unroll
            for (int n = 0; n < 4; ++n)
                #pragma unroll
                for (int i = 0; i < 4; ++i) {
                    const int kvp = kv0 + n * 16 + fq * 4 + i;
                    float sv = s[n][i] * SC;
                    sv = (kvp <= qrow) ? sv : -1e30f;
                    s[n][i] = sv;
                    pm = fmaxf(pm, sv);
                }
        } else {
            #pragma unroll
            for (int n = 0; n < 4; ++n)
                #pragma unroll
                for (int i = 0; i < 4; ++i) {
                    const float sv = s[n][i] * SC;
                    s[n][i] = sv;
                    pm = fmaxf(pm, sv);
                }
        }
        pm = fmaxf(pm, __shfl_xor(pm, 16));
        pm = fmaxf(pm, __shfl_xor(pm, 32));
        const float mnew = fmaxf(m_run, pm);
        const float corr = exp2f(m_run - mnew);
        m_run = mnew;

        float rs = 0.0f;
        unsigned pk[8];
        #pragma unroll
        for (int n = 0; n < 4; ++n) {
            const float p0 = exp2f(s[n][0] - mnew);
            const float p1 = exp2f(s[n][1] - mnew);
            const float p2 = exp2f(s[n][2] - mnew);
            const float p3 = exp2f(s[n][3] - mnew);
            rs += (p0 + p1) + (p2 + p3);
            pk[n * 2 + 0] = pack_bf16(p0, p1);
            pk[n * 2 + 1] = pack_bf16(p2, p3);
        }
        rs += __shfl_xor(rs, 16);
        rs += __shfl_xor(rs, 32);
        l_run = l_run * corr + rs;

        #pragma unroll
        for (int i = 0; i < 4; ++i) {
            const float ci = __shfl(corr, fq * 4 + i);
            o[0][i] *= ci; o[1][i] *= ci; o[2][i] *= ci; o[3][i] *= ci;
        }

        u32x4 A0, A1;
        #pragma unroll
        for (int r = 0; r < 4; ++r) {
            const int sl = fr + ((2 * (fq & 1) + (r >> 1)) << 4);
            const unsigned lo0 = __shfl(pk[0 + (r & 1)], sl);
            const unsigned hi0 = __shfl(pk[2 + (r & 1)], sl);
            const unsigned lo1 = __shfl(pk[4 + (r & 1)], sl);
            const unsigned hi1 = __shfl(pk[6 + (r & 1)], sl);
            A0[r] = (fq & 2) ? hi0 : lo0;
            A1[r] = (fq & 2) ? hi1 : lo1;
        }
        const bf16x8 pa0 = __builtin_bit_cast(bf16x8, A0);
        const bf16x8 pa1 = __builtin_bit_cast(bf16x8, A1);

        #pragma unroll
        for (int tt = 0; tt < 4; ++tt) {
            const int row = tt * 16 + fr;
            const int sw = (row & 7) << 3;
            const bf16x8 v0 = *reinterpret_cast<const bf16x8*>(&Vl[row * 64 + ((fq * 8) ^ sw)]);
            const bf16x8 v1 = *reinterpret_cast<const bf16x8*>(&Vl[row * 64 + ((fq * 8 + 32) ^ sw)]);
            o[tt] = MFMA16(pa0, v0, o[tt]);
            o[tt] = MFMA16(pa1, v1, o[tt]);
        }
        cur ^= 1;
    }

    #pragma unroll
    for (int i = 0; i < 4; ++i) {
        const float li  = __shfl(l_run, fq * 4 + i);
        const float inv = 1.0f / li;
        const int row = q0 + w * 16 + fq * 4 + i;
        #pragma unroll
        for (int tt = 0; tt < 4; ++tt)
            out[(size_t)(b * 2048 + row) * 1024 + h * 64 + tt * 16 + fr] =
                __float2bfloat16(o[tt][i] * inv);
    }
}

// ---------------------------------------------------------------------------
extern "C" void kernel_launch(void* const* d_in, const int* in_sizes, int n_in,
                              void* d_out, int out_size, void* d_ws, size_t ws_size,
                              hipStream_t stream)
{
    (void)in_sizes; (void)n_in; (void)out_size; (void)ws_size;
    const float* x      = (const float*)d_in[0];
    const float* ln1_w  = (const float*)d_in[2];
    const float* ln1_b  = (const float*)d_in[3];
    const float* qkv_w  = (const float*)d_in[4];
    const float* qkv_b  = (const float*)d_in[5];
    const float* proj_w = (const float*)d_in[6];
    const float* proj_b = (const float*)d_in[7];
    const float* ln2_w  = (const float*)d_in[8];
    const float* ln2_b  = (const float*)d_in[9];
    const float* ffn_w1 = (const float*)d_in[10];
    const float* ffn_b1 = (const float*)d_in[11];
    const float* ffn_w2 = (const float*)d_in[12];
    const float* ffn_b2 = (const float*)d_in[13];
    float* outp = (float*)d_out;

    char* ws = (char*)d_ws;
    size_t off = 0;
    auto take = [&](size_t bytes) -> char* {
        char* p = ws + off;
        off += (bytes + 255) & ~(size_t)255;
        return p;
    };
    __hip_bfloat16* wqkv  = (__hip_bfloat16*)take((size_t)3072 * 1024 * 2);  // 6 MB
    __hip_bfloat16* wproj = (__hip_bfloat16*)take((size_t)1024 * 1024 * 2);  // 2 MB
    __hip_bfloat16* wff1  = (__hip_bfloat16*)take((size_t)4096 * 1024 * 2);  // 8 MB
    __hip_bfloat16* wff2  = (__hip_bfloat16*)take((size_t)1024 * 4096 * 2);  // 8 MB
    float*          hbuf  = (float*)take((size_t)4096 * 1024 * 4);           // 16 MB
    __hip_bfloat16* xn    = (__hip_bfloat16*)take((size_t)4096 * 1024 * 2);  // 8 MB
    __hip_bfloat16* qkb   = (__hip_bfloat16*)take((size_t)4096 * 2048 * 2);  // 16 MB
    __hip_bfloat16* Vt    = (__hip_bfloat16*)take((size_t)2048 * 2048 * 2);  // 8 MB
    __hip_bfloat16* attn  = (__hip_bfloat16*)take((size_t)4096 * 1024 * 2);  // 8 MB
    __hip_bfloat16* ffn1  = qkb;  // FFN1 out (32 MB) reuses qkb+Vt+attn

    transpose_to_bf16<<<dim3(3072 / 32, 1024 / 32), 256, 0, stream>>>(qkv_w, wqkv, 1024, 3072);
    transpose_to_bf16<<<dim3(1024 / 32, 1024 / 32), 256, 0, stream>>>(proj_w, wproj, 1024, 1024);
    transpose_to_bf16<<<dim3(4096 / 32, 1024 / 32), 256, 0, stream>>>(ffn_w1, wff1, 1024, 4096);
    transpose_to_bf16<<<dim3(1024 / 32, 4096 / 32), 256, 0, stream>>>(ffn_w2, wff2, 4096, 1024);

    // LN1
    ln_kernel<<<4096, 256, 0, stream>>>(x, ln1_w, ln1_b, xn);
    // QKV (q|k -> qkb, V^T -> Vt)
    gemm128p<3><<<dim3(24, 32), 256, 0, stream>>>(
        xn, wqkv, qkv_b, nullptr, qkb, Vt, 3072, 1024);
    // Attention
    attn_kernel<<<1024, 256, 0, stream>>>(qkb, Vt, attn);
    // proj + residual(x) -> h (fp32)
    gemm128p<0><<<dim3(8, 32), 256, 0, stream>>>(
        attn, wproj, proj_b, x, hbuf, nullptr, 1024, 1024);
    // LN2 -> y
    ln_kernel<<<4096, 256, 0, stream>>>(hbuf, ln2_w, ln2_b, xn);
    // FFN1 + exact GELU
    gemm128p<2><<<dim3(32, 32), 256, 0, stream>>>(
        xn, wff1, ffn_b1, nullptr, ffn1, nullptr, 4096, 1024);
    // FFN2 + bias + residual(h) -> out (fp32), K=4096 unsplit
    gemm128p<0><<<dim3(8, 32), 256, 0, stream>>>(
        ffn1, wff2, ffn_b2, hbuf, outp, nullptr, 1024, 4096);
}